// Round 8
// baseline (506.541 us; speedup 1.0000x reference)
//
#include <hip/hip_runtime.h>
#include <stdint.h>

typedef unsigned short u16;
typedef __bf16 bf16x8 __attribute__((ext_vector_type(8)));
typedef __bf16 bf16x4v __attribute__((ext_vector_type(4)));
typedef float f32x4 __attribute__((ext_vector_type(4)));

typedef __attribute__((address_space(3))) uint32_t lds_u32;
typedef __attribute__((address_space(1))) uint32_t glb_u32;

__device__ __forceinline__ f32x4 mfma16(bf16x8 a, bf16x8 b, f32x4 c) {
    return __builtin_amdgcn_mfma_f32_16x16x32_bf16(a, b, c, 0, 0, 0);
}

__device__ __forceinline__ u16 f2b(float f) {
    union { float f; unsigned u32; } v; v.f = f;
    unsigned b = v.u32;
    unsigned r = b + 0x7FFFu + ((b >> 16) & 1u);   // RNE
    return (u16)(r >> 16);
}

// 4x f32 -> bf16 via native cvt (RNE), reinterpreted as ushort4
__device__ __forceinline__ ushort4 pk4(float a, float b, float c, float d) {
    bf16x4v v;
    v[0] = (__bf16)a; v[1] = (__bf16)b; v[2] = (__bf16)c; v[3] = (__bf16)d;
    union { bf16x4v v; ushort4 u; } cv; cv.v = v; return cv.u;
}

// async global->LDS, 16B per lane (LDS dest = wave base + lane*16)
__device__ __forceinline__ void async16(const u16* g, u16* l) {
    __builtin_amdgcn_global_load_lds((glb_u32*)(uintptr_t)(const void*)g,
                                     (lds_u32*)l, 16, 0, 0);
}

// ---------------------------------------------------------------------------
// fp32 -> bf16 casts
// ---------------------------------------------------------------------------
__global__ __launch_bounds__(256) void cast1(const float* __restrict__ in,
                                             u16* __restrict__ out, int n) {
    const int i = (blockIdx.x * 256 + threadIdx.x) * 4;
    if (i < n) {
        float4 v = *(const float4*)(in + i);
        ushort4 o = { f2b(v.x), f2b(v.y), f2b(v.z), f2b(v.w) };
        *(ushort4*)(out + i) = o;
    }
}

__global__ __launch_bounds__(256) void cast4(
    const float* __restrict__ i0, const float* __restrict__ i1,
    const float* __restrict__ i2, const float* __restrict__ i3,
    u16* __restrict__ o0, u16* __restrict__ o1,
    u16* __restrict__ o2, u16* __restrict__ o3, int n) {
    const int s = blockIdx.y;
    const float* in = s == 0 ? i0 : (s == 1 ? i1 : (s == 2 ? i2 : i3));
    u16* out       = s == 0 ? o0 : (s == 1 ? o1 : (s == 2 ? o2 : o3));
    const int i = (blockIdx.x * 256 + threadIdx.x) * 4;
    if (i < n) {
        float4 v = *(const float4*)(in + i);
        ushort4 o = { f2b(v.x), f2b(v.y), f2b(v.z), f2b(v.w) };
        *(ushort4*)(out + i) = o;
    }
}

__device__ __forceinline__ void store_c(u16* p, float v)   { *p = f2b(v); }
__device__ __forceinline__ void store_c(float* p, float v) { *p = v; }

// ---------------------------------------------------------------------------
// m97-style GEMM (unchanged from round 6/7, passing).
// ---------------------------------------------------------------------------
template <typename OT>
__global__ __launch_bounds__(256) void gemm128(
    const u16* __restrict__ A,
    const u16* __restrict__ W0, const u16* __restrict__ W1, const u16* __restrict__ W2,
    const float* __restrict__ B0, const float* __restrict__ B1, const float* __restrict__ B2,
    OT* __restrict__ O0, OT* __restrict__ O1, OT* __restrict__ O2,
    u16* __restrict__ VT,
    int M, int N, int K)
{
    const int sel = blockIdx.y;
    const u16* W      = sel == 0 ? W0 : (sel == 1 ? W1 : W2);
    const float* bias = sel == 0 ? B0 : (sel == 1 ? B1 : B2);
    OT* O             = sel == 0 ? O0 : (sel == 1 ? O1 : O2);

    __shared__ __attribute__((aligned(16))) u16 As[128 * 32];
    __shared__ __attribute__((aligned(16))) u16 Bs[128 * 32];

    const int tid  = threadIdx.x;
    const int lane = tid & 63;
    const int w    = tid >> 6;
    const int l15  = lane & 15;
    const int quad = lane >> 4;

    const int tn = (blockIdx.x & 7) << 7;
    const int tm = (blockIdx.x >> 3) << 7;
    const int wm = (w >> 1) << 6;
    const int wn = (w & 1) << 6;

    f32x4 acc[4][4];
#pragma unroll
    for (int i = 0; i < 4; ++i)
#pragma unroll
        for (int j = 0; j < 4; ++j) acc[i][j] = f32x4{0.f, 0.f, 0.f, 0.f};

    const int lr = lane >> 2;
    const int lc = (lane & 3) << 3;
    const u16* Ag0 = A + (size_t)(tm + 32 * w + lr) * K + lc;
    const u16* Ag1 = Ag0 + (size_t)16 * K;
    const u16* Wg0 = W + (size_t)(tn + 32 * w + lr) * K + lc;
    const u16* Wg1 = Wg0 + (size_t)16 * K;
    u16* Al0 = &As[(32 * w + lr) * 32 + lc];
    u16* Al1 = &As[(32 * w + 16 + lr) * 32 + lc];
    u16* Bl0 = &Bs[(32 * w + lr) * 32 + lc];
    u16* Bl1 = &Bs[(32 * w + 16 + lr) * 32 + lc];

    for (int k0 = 0; k0 < K; k0 += 32) {
        __syncthreads();
        async16(Ag0 + k0, Al0);
        async16(Ag1 + k0, Al1);
        async16(Wg0 + k0, Bl0);
        async16(Wg1 + k0, Bl1);
        asm volatile("s_waitcnt vmcnt(0)" ::: "memory");
        __syncthreads();

        bf16x8 a[4], b[4];
#pragma unroll
        for (int i = 0; i < 4; ++i)
            a[i] = *(const bf16x8*)&As[(wm + 16 * i + l15) * 32 + quad * 8];
#pragma unroll
        for (int j = 0; j < 4; ++j)
            b[j] = *(const bf16x8*)&Bs[(wn + 16 * j + l15) * 32 + quad * 8];
#pragma unroll
        for (int i = 0; i < 4; ++i)
#pragma unroll
            for (int j = 0; j < 4; ++j)
                acc[i][j] = mfma16(a[i], b[j], acc[i][j]);
    }

    if (VT != nullptr && sel == 2) {
#pragma unroll
        for (int j = 0; j < 4; ++j) {
            const int col = tn + wn + 16 * j + l15;
            const float bj = bias[col];
#pragma unroll
            for (int i = 0; i < 4; ++i) {
                const int row = tm + wm + 16 * i + quad * 4;
                const int bb = row >> 11, s = row & 2047;
                *(ushort4*)&VT[((size_t)(bb << 10) + col) * 2048 + s] =
                    pk4(acc[i][j][0] + bj, acc[i][j][1] + bj,
                        acc[i][j][2] + bj, acc[i][j][3] + bj);
            }
        }
    } else {
#pragma unroll
        for (int j = 0; j < 4; ++j) {
            const int col = tn + wn + 16 * j + l15;
            const float bj = bias[col];
#pragma unroll
            for (int i = 0; i < 4; ++i) {
                const int row = tm + wm + 16 * i + quad * 4;
#pragma unroll
                for (int r = 0; r < 4; ++r)
                    store_c(&O[(size_t)(row + r) * N + col], acc[i][j][r] + bj);
            }
        }
    }
}

// ---------------------------------------------------------------------------
// attn4: causal flash attention, FIXED-MAX softmax + 2-way K-split.
// p_key = exp2(score*SC - 16); no running max, no rescale, l deferred to one
// shfl-reduce at the end. Wave pair (p=0,1) splits the k-tiles of strip-pair
// (sL=j, sH=127-j) by parity; partials merge by plain addition via LDS +
// one block-wide __syncthreads. Scores ~N(0,1) so 2^-16 scaling is exact in
// fp32/bf16 (floating point; relative precision is scale-invariant).
// S^T = K·Q^T (D: row=key, col=q);  O^T = V^T·P^T (D: row=d, col=q).
// ---------------------------------------------------------------------------
__device__ __forceinline__ void load_ktile(const u16* __restrict__ base, int kt,
                                           int l15, int quad, bf16x8 kf[4][2]) {
#pragma unroll
    for (int t = 0; t < 4; ++t) {
        const u16* kp = base + (size_t)(kt * 64 + t * 16 + l15) * 1024 + quad * 8;
        kf[t][0] = *(const bf16x8*)kp;
        kf[t][1] = *(const bf16x8*)(kp + 32);
    }
}
__device__ __forceinline__ void load_vtile(const u16* __restrict__ base, int kt,
                                           int l15, int quad, bf16x8 vf[4][2]) {
#pragma unroll
    for (int t = 0; t < 4; ++t) {
        const u16* vp = base + (size_t)(t * 16 + l15) * 2048 + kt * 64 + quad * 8;
        vf[t][0] = *(const bf16x8*)vp;
        vf[t][1] = *(const bf16x8*)(vp + 32);
    }
}

__global__ __launch_bounds__(256, 4) void attn4(
    const u16* __restrict__ Q, const u16* __restrict__ Kb,
    const u16* __restrict__ VT, u16* __restrict__ ctx)
{
    __shared__ __attribute__((aligned(16))) u16 Pt[4][32][72];     // P round-trip
    __shared__ __attribute__((aligned(16))) float Mg[2][64][34];   // merge buffer

    const int lane = threadIdx.x & 63;
    const int wid  = threadIdx.x >> 6;
    const int l15  = lane & 15;
    const int quad = lane >> 4;
    const int h = blockIdx.y, b = blockIdx.z;
    const int pairIdx = blockIdx.x * 2 + (wid >> 1);   // 0..63
    const int pib = wid >> 1;                          // pair-in-block
    const int p   = wid & 1;                           // k-split parity
    const int sL = pairIdx, sH = 127 - pairIdx;
    const int KL = sL >> 2, KH = sH >> 2;

    const size_t rowbase = (size_t)b * 2048;
    const int cbase = h * 64;
    const u16* kbase = Kb + rowbase * 1024 + cbase;
    const u16* vbase = VT + ((size_t)b * 1024 + cbase) * 2048;

    const int qgL = sL * 16 + l15, qgH = sH * 16 + l15;

    const u16* qpL = Q + (rowbase + qgL) * 1024 + cbase + quad * 8;
    const u16* qpH = Q + (rowbase + qgH) * 1024 + cbase + quad * 8;
    const bf16x8 qL0 = *(const bf16x8*)qpL, qL1 = *(const bf16x8*)(qpL + 32);
    const bf16x8 qH0 = *(const bf16x8*)qpH, qH1 = *(const bf16x8*)(qpH + 32);

    f32x4 oL[4], oH[4];
#pragma unroll
    for (int i = 0; i < 4; ++i) { oL[i] = f32x4{0,0,0,0}; oH[i] = f32x4{0,0,0,0}; }
    float rsL = 0.f, rsH = 0.f;
    const float SC = 0.18033688011112042f;             // 0.125 * log2(e)

    u16 (*ptw)[72] = Pt[wid];

    bf16x8 kc[4][2], kn[4][2], vf[4][2];
    load_ktile(kbase, p, l15, quad, kc);

    for (int kt = p; kt <= KH; kt += 2) {
        load_vtile(vbase, kt, l15, quad, vf);          // consumed after exp
        if (kt + 2 <= KH) load_ktile(kbase, kt + 2, l15, quad, kn);
        const bool doL = (kt <= KL);
        const bool mskH = (kt == KH), mskL = (kt == KL);

        // heavy strip: S^T -> p = exp2(z*SC - 16), accumulate per-lane l
        float pH[4][4], pL[4][4];
#pragma unroll
        for (int t = 0; t < 4; ++t) {
            f32x4 z = {0,0,0,0};
            z = mfma16(kc[t][0], qH0, z);
            z = mfma16(kc[t][1], qH1, z);
#pragma unroll
            for (int r = 0; r < 4; ++r) {
                float v = fmaf(z[r], SC, -16.0f);
                if (mskH && (kt * 64 + t * 16 + quad * 4 + r) > qgH) v = -1e30f;
                const float e = exp2f(v);
                pH[t][r] = e; rsH += e;
            }
        }
        if (doL) {
#pragma unroll
            for (int t = 0; t < 4; ++t) {
                f32x4 z = {0,0,0,0};
                z = mfma16(kc[t][0], qL0, z);
                z = mfma16(kc[t][1], qL1, z);
#pragma unroll
                for (int r = 0; r < 4; ++r) {
                    float v = fmaf(z[r], SC, -16.0f);
                    if (mskL && (kt * 64 + t * 16 + quad * 4 + r) > qgL) v = -1e30f;
                    const float e = exp2f(v);
                    pL[t][r] = e; rsL += e;
                }
            }
        }

        // P (C-layout) -> wave-private LDS rows [q][key]
#pragma unroll
        for (int t = 0; t < 4; ++t)
            *(ushort4*)&ptw[16 + l15][t * 16 + quad * 4] =
                pk4(pH[t][0], pH[t][1], pH[t][2], pH[t][3]);
        if (doL) {
#pragma unroll
            for (int t = 0; t < 4; ++t)
                *(ushort4*)&ptw[l15][t * 16 + quad * 4] =
                    pk4(pL[t][0], pL[t][1], pL[t][2], pL[t][3]);
        }

        const bf16x8 bH0 = *(const bf16x8*)&ptw[16 + l15][quad * 8];
        const bf16x8 bH1 = *(const bf16x8*)&ptw[16 + l15][32 + quad * 8];
#pragma unroll
        for (int t = 0; t < 4; ++t) {
            oH[t] = mfma16(vf[t][0], bH0, oH[t]);
            oH[t] = mfma16(vf[t][1], bH1, oH[t]);
        }
        if (doL) {
            const bf16x8 bL0 = *(const bf16x8*)&ptw[l15][quad * 8];
            const bf16x8 bL1 = *(const bf16x8*)&ptw[l15][32 + quad * 8];
#pragma unroll
            for (int t = 0; t < 4; ++t) {
                oL[t] = mfma16(vf[t][0], bL0, oL[t]);
                oL[t] = mfma16(vf[t][1], bL1, oL[t]);
            }
        }

#pragma unroll
        for (int t = 0; t < 4; ++t) { kc[t][0] = kn[t][0]; kc[t][1] = kn[t][1]; }
    }

    // --- merge the two k-split partials (plain adds; fixed max makes this legal)
    if (p == 1) {
        float* my = &Mg[pib][lane][0];
#pragma unroll
        for (int t = 0; t < 4; ++t)
#pragma unroll
            for (int r = 0; r < 4; ++r) {
                my[t * 4 + r]      = oL[t][r];
                my[16 + t * 4 + r] = oH[t][r];
            }
        my[32] = rsL; my[33] = rsH;
    }
    __syncthreads();
    if (p == 0) {
        const float* ot = &Mg[pib][lane][0];
#pragma unroll
        for (int t = 0; t < 4; ++t)
#pragma unroll
            for (int r = 0; r < 4; ++r) {
                oL[t][r] += ot[t * 4 + r];
                oH[t][r] += ot[16 + t * 4 + r];
            }
        rsL += ot[32]; rsH += ot[33];
        rsL += __shfl_xor(rsL, 16); rsL += __shfl_xor(rsL, 32);
        rsH += __shfl_xor(rsH, 16); rsH += __shfl_xor(rsH, 32);
        const float iL = 1.0f / rsL, iH = 1.0f / rsH;
#pragma unroll
        for (int t = 0; t < 4; ++t) {
            *(ushort4*)&ctx[(rowbase + qgL) * 1024 + cbase + t * 16 + quad * 4] =
                pk4(oL[t][0] * iL, oL[t][1] * iL, oL[t][2] * iL, oL[t][3] * iL);
            *(ushort4*)&ctx[(rowbase + qgH) * 1024 + cbase + t * 16 + quad * 4] =
                pk4(oH[t][0] * iH, oH[t][1] * iH, oH[t][2] * iH, oH[t][3] * iH);
        }
    }
}

extern "C" void kernel_launch(void* const* d_in, const int* in_sizes, int n_in,
                              void* d_out, int out_size, void* d_ws, size_t ws_size,
                              hipStream_t stream) {
    const float* x  = (const float*)d_in[0];
    const float* Wq = (const float*)d_in[1];
    const float* bq = (const float*)d_in[2];
    const float* Wk = (const float*)d_in[3];
    const float* bk = (const float*)d_in[4];
    const float* Wv = (const float*)d_in[5];
    const float* bv = (const float*)d_in[6];
    const float* Wo = (const float*)d_in[7];
    const float* bo = (const float*)d_in[8];
    float* out = (float*)d_out;

    const int N = 1024, K = 1024;
    const int M = in_sizes[0] / K;           // 4096
    const size_t MN = (size_t)M * N;
    const size_t WN = (size_t)N * K;

    u16* xb  = (u16*)d_ws;
    u16* wqb = xb  + MN;
    u16* wkb = wqb + WN;
    u16* wvb = wkb + WN;
    u16* wob = wvb + WN;
    u16* q   = wob + WN;
    u16* kb  = q   + MN;
    u16* vt  = kb  + MN;                     // V^T: [b*1024 + h*64 + d][s]
    u16* ctx = q;                            // alias: disjoint per-wave strips

    cast1<<<dim3((int)(MN / 4 / 256)), 256, 0, stream>>>(x, xb, (int)MN);
    cast4<<<dim3((int)(WN / 4 / 256), 4), 256, 0, stream>>>(
        Wq, Wk, Wv, Wo, wqb, wkb, wvb, wob, (int)WN);

    const int gemmBlocks = (M / 128) * (N / 128);     // 256

    gemm128<u16><<<dim3(gemmBlocks, 3), 256, 0, stream>>>(
        xb, wqb, wkb, wvb, bq, bk, bv, q, kb, /*unused*/ q, vt, M, N, K);

    // 64 pairs per (b,h), 2 pairs per block, 2-way k-split -> 32 blocks
    attn4<<<dim3(32, 16, 2), 256, 0, stream>>>(q, kb, vt, ctx);

    gemm128<float><<<dim3(gemmBlocks, 1), 256, 0, stream>>>(
        ctx, wob, wob, wob, bo, bo, bo, out, out, out, nullptr, M, N, K);
}

// Round 9
// 290.461 us; speedup vs baseline: 1.7439x; 1.7439x over previous
//
#include <hip/hip_runtime.h>
#include <stdint.h>

typedef unsigned short u16;
typedef __bf16 bf16x8 __attribute__((ext_vector_type(8)));
typedef __bf16 bf16x4v __attribute__((ext_vector_type(4)));
typedef float f32x4 __attribute__((ext_vector_type(4)));

typedef __attribute__((address_space(3))) uint32_t lds_u32;
typedef __attribute__((address_space(1))) uint32_t glb_u32;

__device__ __forceinline__ f32x4 mfma16(bf16x8 a, bf16x8 b, f32x4 c) {
    return __builtin_amdgcn_mfma_f32_16x16x32_bf16(a, b, c, 0, 0, 0);
}

__device__ __forceinline__ u16 f2b(float f) {
    union { float f; unsigned u32; } v; v.f = f;
    unsigned b = v.u32;
    unsigned r = b + 0x7FFFu + ((b >> 16) & 1u);   // RNE
    return (u16)(r >> 16);
}

// 4x f32 -> bf16 via native cvt (RNE), reinterpreted as ushort4
__device__ __forceinline__ ushort4 pk4(float a, float b, float c, float d) {
    bf16x4v v;
    v[0] = (__bf16)a; v[1] = (__bf16)b; v[2] = (__bf16)c; v[3] = (__bf16)d;
    union { bf16x4v v; ushort4 u; } cv; cv.v = v; return cv.u;
}

// async global->LDS, 16B per lane (LDS dest = wave base + lane*16)
__device__ __forceinline__ void async16(const u16* g, u16* l) {
    __builtin_amdgcn_global_load_lds((glb_u32*)(uintptr_t)(const void*)g,
                                     (lds_u32*)l, 16, 0, 0);
}

// ---------------------------------------------------------------------------
// fp32 -> bf16 casts
// ---------------------------------------------------------------------------
__global__ __launch_bounds__(256) void cast1(const float* __restrict__ in,
                                             u16* __restrict__ out, int n) {
    const int i = (blockIdx.x * 256 + threadIdx.x) * 4;
    if (i < n) {
        float4 v = *(const float4*)(in + i);
        ushort4 o = { f2b(v.x), f2b(v.y), f2b(v.z), f2b(v.w) };
        *(ushort4*)(out + i) = o;
    }
}

__global__ __launch_bounds__(256) void cast4(
    const float* __restrict__ i0, const float* __restrict__ i1,
    const float* __restrict__ i2, const float* __restrict__ i3,
    u16* __restrict__ o0, u16* __restrict__ o1,
    u16* __restrict__ o2, u16* __restrict__ o3, int n) {
    const int s = blockIdx.y;
    const float* in = s == 0 ? i0 : (s == 1 ? i1 : (s == 2 ? i2 : i3));
    u16* out       = s == 0 ? o0 : (s == 1 ? o1 : (s == 2 ? o2 : o3));
    const int i = (blockIdx.x * 256 + threadIdx.x) * 4;
    if (i < n) {
        float4 v = *(const float4*)(in + i);
        ushort4 o = { f2b(v.x), f2b(v.y), f2b(v.z), f2b(v.w) };
        *(ushort4*)(out + i) = o;
    }
}

__device__ __forceinline__ void store_c(u16* p, float v)   { *p = f2b(v); }
__device__ __forceinline__ void store_c(float* p, float v) { *p = v; }

// ---------------------------------------------------------------------------
// m97-style GEMM (unchanged, passing since round 5).
// ---------------------------------------------------------------------------
template <typename OT>
__global__ __launch_bounds__(256) void gemm128(
    const u16* __restrict__ A,
    const u16* __restrict__ W0, const u16* __restrict__ W1, const u16* __restrict__ W2,
    const float* __restrict__ B0, const float* __restrict__ B1, const float* __restrict__ B2,
    OT* __restrict__ O0, OT* __restrict__ O1, OT* __restrict__ O2,
    u16* __restrict__ VT,
    int M, int N, int K)
{
    const int sel = blockIdx.y;
    const u16* W      = sel == 0 ? W0 : (sel == 1 ? W1 : W2);
    const float* bias = sel == 0 ? B0 : (sel == 1 ? B1 : B2);
    OT* O             = sel == 0 ? O0 : (sel == 1 ? O1 : O2);

    __shared__ __attribute__((aligned(16))) u16 As[128 * 32];
    __shared__ __attribute__((aligned(16))) u16 Bs[128 * 32];

    const int tid  = threadIdx.x;
    const int lane = tid & 63;
    const int w    = tid >> 6;
    const int l15  = lane & 15;
    const int quad = lane >> 4;

    const int tn = (blockIdx.x & 7) << 7;
    const int tm = (blockIdx.x >> 3) << 7;
    const int wm = (w >> 1) << 6;
    const int wn = (w & 1) << 6;

    f32x4 acc[4][4];
#pragma unroll
    for (int i = 0; i < 4; ++i)
#pragma unroll
        for (int j = 0; j < 4; ++j) acc[i][j] = f32x4{0.f, 0.f, 0.f, 0.f};

    const int lr = lane >> 2;
    const int lc = (lane & 3) << 3;
    const u16* Ag0 = A + (size_t)(tm + 32 * w + lr) * K + lc;
    const u16* Ag1 = Ag0 + (size_t)16 * K;
    const u16* Wg0 = W + (size_t)(tn + 32 * w + lr) * K + lc;
    const u16* Wg1 = Wg0 + (size_t)16 * K;
    u16* Al0 = &As[(32 * w + lr) * 32 + lc];
    u16* Al1 = &As[(32 * w + 16 + lr) * 32 + lc];
    u16* Bl0 = &Bs[(32 * w + lr) * 32 + lc];
    u16* Bl1 = &Bs[(32 * w + 16 + lr) * 32 + lc];

    for (int k0 = 0; k0 < K; k0 += 32) {
        __syncthreads();
        async16(Ag0 + k0, Al0);
        async16(Ag1 + k0, Al1);
        async16(Wg0 + k0, Bl0);
        async16(Wg1 + k0, Bl1);
        asm volatile("s_waitcnt vmcnt(0)" ::: "memory");
        __syncthreads();

        bf16x8 a[4], b[4];
#pragma unroll
        for (int i = 0; i < 4; ++i)
            a[i] = *(const bf16x8*)&As[(wm + 16 * i + l15) * 32 + quad * 8];
#pragma unroll
        for (int j = 0; j < 4; ++j)
            b[j] = *(const bf16x8*)&Bs[(wn + 16 * j + l15) * 32 + quad * 8];
#pragma unroll
        for (int i = 0; i < 4; ++i)
#pragma unroll
            for (int j = 0; j < 4; ++j)
                acc[i][j] = mfma16(a[i], b[j], acc[i][j]);
    }

    if (VT != nullptr && sel == 2) {
#pragma unroll
        for (int j = 0; j < 4; ++j) {
            const int col = tn + wn + 16 * j + l15;
            const float bj = bias[col];
#pragma unroll
            for (int i = 0; i < 4; ++i) {
                const int row = tm + wm + 16 * i + quad * 4;
                const int bb = row >> 11, s = row & 2047;
                *(ushort4*)&VT[((size_t)(bb << 10) + col) * 2048 + s] =
                    pk4(acc[i][j][0] + bj, acc[i][j][1] + bj,
                        acc[i][j][2] + bj, acc[i][j][3] + bj);
            }
        }
    } else {
#pragma unroll
        for (int j = 0; j < 4; ++j) {
            const int col = tn + wn + 16 * j + l15;
            const float bj = bias[col];
#pragma unroll
            for (int i = 0; i < 4; ++i) {
                const int row = tm + wm + 16 * i + quad * 4;
#pragma unroll
                for (int r = 0; r < 4; ++r)
                    store_c(&O[(size_t)(row + r) * N + col], acc[i][j][r] + bj);
            }
        }
    }
}

// ---------------------------------------------------------------------------
// attn4: causal flash attention, FIXED-MAX softmax + 2-way K-split.
// p_key = exp2(score*SC - 16); no running max, no rescale; l deferred to one
// shfl-reduce at the end. Wave pair (p=0,1) splits the k-tiles of strip-pair
// (sL=j, sH=127-j) by parity; partials merge by plain addition via LDS +
// one block-wide __syncthreads.
// NOTE: __launch_bounds__(256) only — round 8's (256,4) capped VGPR at 64 and
// spilled ~1.3 GB to scratch (WRITE_SIZE 774 MB). Natural allocation ~150-170
// VGPR; LDS (35.8 KB) caps residency at ~3-4 blocks/CU which is enough TLP.
// ---------------------------------------------------------------------------
__device__ __forceinline__ void load_ktile(const u16* __restrict__ base, int kt,
                                           int l15, int quad, bf16x8 kf[4][2]) {
#pragma unroll
    for (int t = 0; t < 4; ++t) {
        const u16* kp = base + (size_t)(kt * 64 + t * 16 + l15) * 1024 + quad * 8;
        kf[t][0] = *(const bf16x8*)kp;
        kf[t][1] = *(const bf16x8*)(kp + 32);
    }
}
__device__ __forceinline__ void load_vtile(const u16* __restrict__ base, int kt,
                                           int l15, int quad, bf16x8 vf[4][2]) {
#pragma unroll
    for (int t = 0; t < 4; ++t) {
        const u16* vp = base + (size_t)(t * 16 + l15) * 2048 + kt * 64 + quad * 8;
        vf[t][0] = *(const bf16x8*)vp;
        vf[t][1] = *(const bf16x8*)(vp + 32);
    }
}

__global__ __launch_bounds__(256) void attn4(
    const u16* __restrict__ Q, const u16* __restrict__ Kb,
    const u16* __restrict__ VT, u16* __restrict__ ctx)
{
    __shared__ __attribute__((aligned(16))) u16 Pt[4][32][72];     // P round-trip
    __shared__ __attribute__((aligned(16))) float Mg[2][64][34];   // merge buffer

    const int lane = threadIdx.x & 63;
    const int wid  = threadIdx.x >> 6;
    const int l15  = lane & 15;
    const int quad = lane >> 4;
    const int h = blockIdx.y, b = blockIdx.z;
    const int pairIdx = blockIdx.x * 2 + (wid >> 1);   // 0..63
    const int pib = wid >> 1;                          // pair-in-block
    const int p   = wid & 1;                           // k-split parity
    const int sL = pairIdx, sH = 127 - pairIdx;
    const int KL = sL >> 2, KH = sH >> 2;

    const size_t rowbase = (size_t)b * 2048;
    const int cbase = h * 64;
    const u16* kbase = Kb + rowbase * 1024 + cbase;
    const u16* vbase = VT + ((size_t)b * 1024 + cbase) * 2048;

    const int qgL = sL * 16 + l15, qgH = sH * 16 + l15;

    const u16* qpL = Q + (rowbase + qgL) * 1024 + cbase + quad * 8;
    const u16* qpH = Q + (rowbase + qgH) * 1024 + cbase + quad * 8;
    const bf16x8 qL0 = *(const bf16x8*)qpL, qL1 = *(const bf16x8*)(qpL + 32);
    const bf16x8 qH0 = *(const bf16x8*)qpH, qH1 = *(const bf16x8*)(qpH + 32);

    f32x4 oL[4], oH[4];
#pragma unroll
    for (int i = 0; i < 4; ++i) { oL[i] = f32x4{0,0,0,0}; oH[i] = f32x4{0,0,0,0}; }
    float rsL = 0.f, rsH = 0.f;
    const float SC = 0.18033688011112042f;             // 0.125 * log2(e)

    u16 (*ptw)[72] = Pt[wid];

    bf16x8 kc[4][2], kn[4][2], vf[4][2];
    load_ktile(kbase, p, l15, quad, kc);

    for (int kt = p; kt <= KH; kt += 2) {
        load_vtile(vbase, kt, l15, quad, vf);          // consumed after exp
        if (kt + 2 <= KH) load_ktile(kbase, kt + 2, l15, quad, kn);
        const bool doL = (kt <= KL);
        const bool mskH = (kt == KH), mskL = (kt == KL);

        float pH[4][4], pL[4][4];
#pragma unroll
        for (int t = 0; t < 4; ++t) {
            f32x4 z = {0,0,0,0};
            z = mfma16(kc[t][0], qH0, z);
            z = mfma16(kc[t][1], qH1, z);
#pragma unroll
            for (int r = 0; r < 4; ++r) {
                float v = fmaf(z[r], SC, -16.0f);
                if (mskH && (kt * 64 + t * 16 + quad * 4 + r) > qgH) v = -1e30f;
                const float e = exp2f(v);
                pH[t][r] = e; rsH += e;
            }
        }
        if (doL) {
#pragma unroll
            for (int t = 0; t < 4; ++t) {
                f32x4 z = {0,0,0,0};
                z = mfma16(kc[t][0], qL0, z);
                z = mfma16(kc[t][1], qL1, z);
#pragma unroll
                for (int r = 0; r < 4; ++r) {
                    float v = fmaf(z[r], SC, -16.0f);
                    if (mskL && (kt * 64 + t * 16 + quad * 4 + r) > qgL) v = -1e30f;
                    const float e = exp2f(v);
                    pL[t][r] = e; rsL += e;
                }
            }
        }

        // P (C-layout) -> wave-private LDS rows [q][key]
#pragma unroll
        for (int t = 0; t < 4; ++t)
            *(ushort4*)&ptw[16 + l15][t * 16 + quad * 4] =
                pk4(pH[t][0], pH[t][1], pH[t][2], pH[t][3]);
        if (doL) {
#pragma unroll
            for (int t = 0; t < 4; ++t)
                *(ushort4*)&ptw[l15][t * 16 + quad * 4] =
                    pk4(pL[t][0], pL[t][1], pL[t][2], pL[t][3]);
        }

        const bf16x8 bH0 = *(const bf16x8*)&ptw[16 + l15][quad * 8];
        const bf16x8 bH1 = *(const bf16x8*)&ptw[16 + l15][32 + quad * 8];
#pragma unroll
        for (int t = 0; t < 4; ++t) {
            oH[t] = mfma16(vf[t][0], bH0, oH[t]);
            oH[t] = mfma16(vf[t][1], bH1, oH[t]);
        }
        if (doL) {
            const bf16x8 bL0 = *(const bf16x8*)&ptw[l15][quad * 8];
            const bf16x8 bL1 = *(const bf16x8*)&ptw[l15][32 + quad * 8];
#pragma unroll
            for (int t = 0; t < 4; ++t) {
                oL[t] = mfma16(vf[t][0], bL0, oL[t]);
                oL[t] = mfma16(vf[t][1], bL1, oL[t]);
            }
        }

#pragma unroll
        for (int t = 0; t < 4; ++t) { kc[t][0] = kn[t][0]; kc[t][1] = kn[t][1]; }
    }

    // merge the two k-split partials (plain adds; fixed max makes this legal)
    if (p == 1) {
        float* my = &Mg[pib][lane][0];
#pragma unroll
        for (int t = 0; t < 4; ++t)
#pragma unroll
            for (int r = 0; r < 4; ++r) {
                my[t * 4 + r]      = oL[t][r];
                my[16 + t * 4 + r] = oH[t][r];
            }
        my[32] = rsL; my[33] = rsH;
    }
    __syncthreads();
    if (p == 0) {
        const float* ot = &Mg[pib][lane][0];
#pragma unroll
        for (int t = 0; t < 4; ++t)
#pragma unroll
            for (int r = 0; r < 4; ++r) {
                oL[t][r] += ot[t * 4 + r];
                oH[t][r] += ot[16 + t * 4 + r];
            }
        rsL += ot[32]; rsH += ot[33];
        rsL += __shfl_xor(rsL, 16); rsL += __shfl_xor(rsL, 32);
        rsH += __shfl_xor(rsH, 16); rsH += __shfl_xor(rsH, 32);
        const float iL = 1.0f / rsL, iH = 1.0f / rsH;
#pragma unroll
        for (int t = 0; t < 4; ++t) {
            *(ushort4*)&ctx[(rowbase + qgL) * 1024 + cbase + t * 16 + quad * 4] =
                pk4(oL[t][0] * iL, oL[t][1] * iL, oL[t][2] * iL, oL[t][3] * iL);
            *(ushort4*)&ctx[(rowbase + qgH) * 1024 + cbase + t * 16 + quad * 4] =
                pk4(oH[t][0] * iH, oH[t][1] * iH, oH[t][2] * iH, oH[t][3] * iH);
        }
    }
}

extern "C" void kernel_launch(void* const* d_in, const int* in_sizes, int n_in,
                              void* d_out, int out_size, void* d_ws, size_t ws_size,
                              hipStream_t stream) {
    const float* x  = (const float*)d_in[0];
    const float* Wq = (const float*)d_in[1];
    const float* bq = (const float*)d_in[2];
    const float* Wk = (const float*)d_in[3];
    const float* bk = (const float*)d_in[4];
    const float* Wv = (const float*)d_in[5];
    const float* bv = (const float*)d_in[6];
    const float* Wo = (const float*)d_in[7];
    const float* bo = (const float*)d_in[8];
    float* out = (float*)d_out;

    const int N = 1024, K = 1024;
    const int M = in_sizes[0] / K;           // 4096
    const size_t MN = (size_t)M * N;
    const size_t WN = (size_t)N * K;

    u16* xb  = (u16*)d_ws;
    u16* wqb = xb  + MN;
    u16* wkb = wqb + WN;
    u16* wvb = wkb + WN;
    u16* wob = wvb + WN;
    u16* q   = wob + WN;
    u16* kb  = q   + MN;
    u16* vt  = kb  + MN;                     // V^T: [b*1024 + h*64 + d][s]
    u16* ctx = q;                            // alias: disjoint per-wave strips

    cast1<<<dim3((int)(MN / 4 / 256)), 256, 0, stream>>>(x, xb, (int)MN);
    cast4<<<dim3((int)(WN / 4 / 256), 4), 256, 0, stream>>>(
        Wq, Wk, Wv, Wo, wqb, wkb, wvb, wob, (int)WN);

    const int gemmBlocks = (M / 128) * (N / 128);     // 256

    gemm128<u16><<<dim3(gemmBlocks, 3), 256, 0, stream>>>(
        xb, wqb, wkb, wvb, bq, bk, bv, q, kb, /*unused*/ q, vt, M, N, K);

    attn4<<<dim3(32, 16, 2), 256, 0, stream>>>(q, kb, vt, ctx);

    gemm128<float><<<dim3(gemmBlocks, 1), 256, 0, stream>>>(
        ctx, wob, wob, wob, bo, bo, bo, out, out, out, nullptr, M, N, K);
}

// Round 10
// 264.762 us; speedup vs baseline: 1.9132x; 1.0971x over previous
//
#include <hip/hip_runtime.h>
#include <stdint.h>

typedef unsigned short u16;
typedef __bf16 bf16x8 __attribute__((ext_vector_type(8)));
typedef __bf16 bf16x4v __attribute__((ext_vector_type(4)));
typedef float f32x4 __attribute__((ext_vector_type(4)));

typedef __attribute__((address_space(3))) uint32_t lds_u32;
typedef __attribute__((address_space(1))) uint32_t glb_u32;

__device__ __forceinline__ f32x4 mfma16(bf16x8 a, bf16x8 b, f32x4 c) {
    return __builtin_amdgcn_mfma_f32_16x16x32_bf16(a, b, c, 0, 0, 0);
}

__device__ __forceinline__ u16 f2b(float f) {
    union { float f; unsigned u32; } v; v.f = f;
    unsigned b = v.u32;
    unsigned r = b + 0x7FFFu + ((b >> 16) & 1u);   // RNE
    return (u16)(r >> 16);
}

// 4x f32 -> bf16 via native cvt (RNE), reinterpreted as ushort4
__device__ __forceinline__ ushort4 pk4(float a, float b, float c, float d) {
    bf16x4v v;
    v[0] = (__bf16)a; v[1] = (__bf16)b; v[2] = (__bf16)c; v[3] = (__bf16)d;
    union { bf16x4v v; ushort4 u; } cv; cv.v = v; return cv.u;
}

// async global->LDS, 16B per lane (LDS dest = wave base + lane*16)
__device__ __forceinline__ void async16(const u16* g, u16* l) {
    __builtin_amdgcn_global_load_lds((glb_u32*)(uintptr_t)(const void*)g,
                                     (lds_u32*)l, 16, 0, 0);
}

// ---------------------------------------------------------------------------
// fp32 -> bf16 casts
// ---------------------------------------------------------------------------
__global__ __launch_bounds__(256) void cast1(const float* __restrict__ in,
                                             u16* __restrict__ out, int n) {
    const int i = (blockIdx.x * 256 + threadIdx.x) * 4;
    if (i < n) {
        float4 v = *(const float4*)(in + i);
        ushort4 o = { f2b(v.x), f2b(v.y), f2b(v.z), f2b(v.w) };
        *(ushort4*)(out + i) = o;
    }
}

__global__ __launch_bounds__(256) void cast4(
    const float* __restrict__ i0, const float* __restrict__ i1,
    const float* __restrict__ i2, const float* __restrict__ i3,
    u16* __restrict__ o0, u16* __restrict__ o1,
    u16* __restrict__ o2, u16* __restrict__ o3, int n) {
    const int s = blockIdx.y;
    const float* in = s == 0 ? i0 : (s == 1 ? i1 : (s == 2 ? i2 : i3));
    u16* out       = s == 0 ? o0 : (s == 1 ? o1 : (s == 2 ? o2 : o3));
    const int i = (blockIdx.x * 256 + threadIdx.x) * 4;
    if (i < n) {
        float4 v = *(const float4*)(in + i);
        ushort4 o = { f2b(v.x), f2b(v.y), f2b(v.z), f2b(v.w) };
        *(ushort4*)(out + i) = o;
    }
}

__device__ __forceinline__ void store_c(u16* p, float v)   { *p = f2b(v); }
__device__ __forceinline__ void store_c(float* p, float v) { *p = v; }

// ---------------------------------------------------------------------------
// m97-style GEMM (unchanged, passing since round 5).
// ---------------------------------------------------------------------------
template <typename OT>
__global__ __launch_bounds__(256) void gemm128(
    const u16* __restrict__ A,
    const u16* __restrict__ W0, const u16* __restrict__ W1, const u16* __restrict__ W2,
    const float* __restrict__ B0, const float* __restrict__ B1, const float* __restrict__ B2,
    OT* __restrict__ O0, OT* __restrict__ O1, OT* __restrict__ O2,
    u16* __restrict__ VT,
    int M, int N, int K)
{
    const int sel = blockIdx.y;
    const u16* W      = sel == 0 ? W0 : (sel == 1 ? W1 : W2);
    const float* bias = sel == 0 ? B0 : (sel == 1 ? B1 : B2);
    OT* O             = sel == 0 ? O0 : (sel == 1 ? O1 : O2);

    __shared__ __attribute__((aligned(16))) u16 As[128 * 32];
    __shared__ __attribute__((aligned(16))) u16 Bs[128 * 32];

    const int tid  = threadIdx.x;
    const int lane = tid & 63;
    const int w    = tid >> 6;
    const int l15  = lane & 15;
    const int quad = lane >> 4;

    const int tn = (blockIdx.x & 7) << 7;
    const int tm = (blockIdx.x >> 3) << 7;
    const int wm = (w >> 1) << 6;
    const int wn = (w & 1) << 6;

    f32x4 acc[4][4];
#pragma unroll
    for (int i = 0; i < 4; ++i)
#pragma unroll
        for (int j = 0; j < 4; ++j) acc[i][j] = f32x4{0.f, 0.f, 0.f, 0.f};

    const int lr = lane >> 2;
    const int lc = (lane & 3) << 3;
    const u16* Ag0 = A + (size_t)(tm + 32 * w + lr) * K + lc;
    const u16* Ag1 = Ag0 + (size_t)16 * K;
    const u16* Wg0 = W + (size_t)(tn + 32 * w + lr) * K + lc;
    const u16* Wg1 = Wg0 + (size_t)16 * K;
    u16* Al0 = &As[(32 * w + lr) * 32 + lc];
    u16* Al1 = &As[(32 * w + 16 + lr) * 32 + lc];
    u16* Bl0 = &Bs[(32 * w + lr) * 32 + lc];
    u16* Bl1 = &Bs[(32 * w + 16 + lr) * 32 + lc];

    for (int k0 = 0; k0 < K; k0 += 32) {
        __syncthreads();
        async16(Ag0 + k0, Al0);
        async16(Ag1 + k0, Al1);
        async16(Wg0 + k0, Bl0);
        async16(Wg1 + k0, Bl1);
        asm volatile("s_waitcnt vmcnt(0)" ::: "memory");
        __syncthreads();

        bf16x8 a[4], b[4];
#pragma unroll
        for (int i = 0; i < 4; ++i)
            a[i] = *(const bf16x8*)&As[(wm + 16 * i + l15) * 32 + quad * 8];
#pragma unroll
        for (int j = 0; j < 4; ++j)
            b[j] = *(const bf16x8*)&Bs[(wn + 16 * j + l15) * 32 + quad * 8];
#pragma unroll
        for (int i = 0; i < 4; ++i)
#pragma unroll
            for (int j = 0; j < 4; ++j)
                acc[i][j] = mfma16(a[i], b[j], acc[i][j]);
    }

    if (VT != nullptr && sel == 2) {
#pragma unroll
        for (int j = 0; j < 4; ++j) {
            const int col = tn + wn + 16 * j + l15;
            const float bj = bias[col];
#pragma unroll
            for (int i = 0; i < 4; ++i) {
                const int row = tm + wm + 16 * i + quad * 4;
                const int bb = row >> 11, s = row & 2047;
                *(ushort4*)&VT[((size_t)(bb << 10) + col) * 2048 + s] =
                    pk4(acc[i][j][0] + bj, acc[i][j][1] + bj,
                        acc[i][j][2] + bj, acc[i][j][3] + bj);
            }
        }
    } else {
#pragma unroll
        for (int j = 0; j < 4; ++j) {
            const int col = tn + wn + 16 * j + l15;
            const float bj = bias[col];
#pragma unroll
            for (int i = 0; i < 4; ++i) {
                const int row = tm + wm + 16 * i + quad * 4;
#pragma unroll
                for (int r = 0; r < 4; ++r)
                    store_c(&O[(size_t)(row + r) * N + col], acc[i][j][r] + bj);
            }
        }
    }
}

// ---------------------------------------------------------------------------
// attn5: fixed-max softmax + 2-way K-split (numerics identical to round 9's
// passing attn4), with an XCD-locality block swizzle: 1D grid, (h,b) in the
// LOW 5 bits of blockIdx.x so that id%8 XCD round-robin gives each XCD only
// 4 distinct (b,h) working sets (~3 MB < 4 MB per-XCD L2). Round-9 layout
// spread all 32 (b,h) across every XCD -> 16 MB working set -> L2 thrash
// (FETCH 67 MB vs 24 MB ideal, ~900cyc HBM-latency loads).
// ---------------------------------------------------------------------------
__device__ __forceinline__ void load_ktile(const u16* __restrict__ base, int kt,
                                           int l15, int quad, bf16x8 kf[4][2]) {
#pragma unroll
    for (int t = 0; t < 4; ++t) {
        const u16* kp = base + (size_t)(kt * 64 + t * 16 + l15) * 1024 + quad * 8;
        kf[t][0] = *(const bf16x8*)kp;
        kf[t][1] = *(const bf16x8*)(kp + 32);
    }
}
__device__ __forceinline__ void load_vtile(const u16* __restrict__ base, int kt,
                                           int l15, int quad, bf16x8 vf[4][2]) {
#pragma unroll
    for (int t = 0; t < 4; ++t) {
        const u16* vp = base + (size_t)(t * 16 + l15) * 2048 + kt * 64 + quad * 8;
        vf[t][0] = *(const bf16x8*)vp;
        vf[t][1] = *(const bf16x8*)(vp + 32);
    }
}

__global__ __launch_bounds__(256) void attn5(
    const u16* __restrict__ Q, const u16* __restrict__ Kb,
    const u16* __restrict__ VT, u16* __restrict__ ctx)
{
    __shared__ __attribute__((aligned(16))) u16 Pt[4][32][72];     // P round-trip
    __shared__ __attribute__((aligned(16))) float Mg[2][64][34];   // merge buffer

    const int lane = threadIdx.x & 63;
    const int wid  = threadIdx.x >> 6;
    const int l15  = lane & 15;
    const int quad = lane >> 4;

    // XCD-locality decode: low 5 bits = (h,b), high bits = pair group
    const int hb = blockIdx.x & 31;
    const int h  = hb & 15;
    const int b  = hb >> 4;
    const int pairGroup = blockIdx.x >> 5;             // 0..31

    const int pairIdx = pairGroup * 2 + (wid >> 1);    // 0..63
    const int pib = wid >> 1;                          // pair-in-block
    const int p   = wid & 1;                           // k-split parity
    const int sL = pairIdx, sH = 127 - pairIdx;
    const int KL = sL >> 2, KH = sH >> 2;

    const size_t rowbase = (size_t)b * 2048;
    const int cbase = h * 64;
    const u16* kbase = Kb + rowbase * 1024 + cbase;
    const u16* vbase = VT + ((size_t)b * 1024 + cbase) * 2048;

    const int qgL = sL * 16 + l15, qgH = sH * 16 + l15;

    const u16* qpL = Q + (rowbase + qgL) * 1024 + cbase + quad * 8;
    const u16* qpH = Q + (rowbase + qgH) * 1024 + cbase + quad * 8;
    const bf16x8 qL0 = *(const bf16x8*)qpL, qL1 = *(const bf16x8*)(qpL + 32);
    const bf16x8 qH0 = *(const bf16x8*)qpH, qH1 = *(const bf16x8*)(qpH + 32);

    f32x4 oL[4], oH[4];
#pragma unroll
    for (int i = 0; i < 4; ++i) { oL[i] = f32x4{0,0,0,0}; oH[i] = f32x4{0,0,0,0}; }
    float rsL = 0.f, rsH = 0.f;
    const float SC = 0.18033688011112042f;             // 0.125 * log2(e)

    u16 (*ptw)[72] = Pt[wid];

    bf16x8 kc[4][2], kn[4][2], vf[4][2];
    load_ktile(kbase, p, l15, quad, kc);

    for (int kt = p; kt <= KH; kt += 2) {
        load_vtile(vbase, kt, l15, quad, vf);          // consumed after exp
        if (kt + 2 <= KH) load_ktile(kbase, kt + 2, l15, quad, kn);
        const bool doL = (kt <= KL);
        const bool mskH = (kt == KH), mskL = (kt == KL);

        float pH[4][4], pL[4][4];
#pragma unroll
        for (int t = 0; t < 4; ++t) {
            f32x4 z = {0,0,0,0};
            z = mfma16(kc[t][0], qH0, z);
            z = mfma16(kc[t][1], qH1, z);
#pragma unroll
            for (int r = 0; r < 4; ++r) {
                float v = fmaf(z[r], SC, -16.0f);
                if (mskH && (kt * 64 + t * 16 + quad * 4 + r) > qgH) v = -1e30f;
                const float e = exp2f(v);
                pH[t][r] = e; rsH += e;
            }
        }
        if (doL) {
#pragma unroll
            for (int t = 0; t < 4; ++t) {
                f32x4 z = {0,0,0,0};
                z = mfma16(kc[t][0], qL0, z);
                z = mfma16(kc[t][1], qL1, z);
#pragma unroll
                for (int r = 0; r < 4; ++r) {
                    float v = fmaf(z[r], SC, -16.0f);
                    if (mskL && (kt * 64 + t * 16 + quad * 4 + r) > qgL) v = -1e30f;
                    const float e = exp2f(v);
                    pL[t][r] = e; rsL += e;
                }
            }
        }

        // P (C-layout) -> wave-private LDS rows [q][key]
#pragma unroll
        for (int t = 0; t < 4; ++t)
            *(ushort4*)&ptw[16 + l15][t * 16 + quad * 4] =
                pk4(pH[t][0], pH[t][1], pH[t][2], pH[t][3]);
        if (doL) {
#pragma unroll
            for (int t = 0; t < 4; ++t)
                *(ushort4*)&ptw[l15][t * 16 + quad * 4] =
                    pk4(pL[t][0], pL[t][1], pL[t][2], pL[t][3]);
        }

        const bf16x8 bH0 = *(const bf16x8*)&ptw[16 + l15][quad * 8];
        const bf16x8 bH1 = *(const bf16x8*)&ptw[16 + l15][32 + quad * 8];
#pragma unroll
        for (int t = 0; t < 4; ++t) {
            oH[t] = mfma16(vf[t][0], bH0, oH[t]);
            oH[t] = mfma16(vf[t][1], bH1, oH[t]);
        }
        if (doL) {
            const bf16x8 bL0 = *(const bf16x8*)&ptw[l15][quad * 8];
            const bf16x8 bL1 = *(const bf16x8*)&ptw[l15][32 + quad * 8];
#pragma unroll
            for (int t = 0; t < 4; ++t) {
                oL[t] = mfma16(vf[t][0], bL0, oL[t]);
                oL[t] = mfma16(vf[t][1], bL1, oL[t]);
            }
        }

#pragma unroll
        for (int t = 0; t < 4; ++t) { kc[t][0] = kn[t][0]; kc[t][1] = kn[t][1]; }
    }

    // merge the two k-split partials (plain adds; fixed max makes this legal)
    if (p == 1) {
        float* my = &Mg[pib][lane][0];
#pragma unroll
        for (int t = 0; t < 4; ++t)
#pragma unroll
            for (int r = 0; r < 4; ++r) {
                my[t * 4 + r]      = oL[t][r];
                my[16 + t * 4 + r] = oH[t][r];
            }
        my[32] = rsL; my[33] = rsH;
    }
    __syncthreads();
    if (p == 0) {
        const float* ot = &Mg[pib][lane][0];
#pragma unroll
        for (int t = 0; t < 4; ++t)
#pragma unroll
            for (int r = 0; r < 4; ++r) {
                oL[t][r] += ot[t * 4 + r];
                oH[t][r] += ot[16 + t * 4 + r];
            }
        rsL += ot[32]; rsH += ot[33];
        rsL += __shfl_xor(rsL, 16); rsL += __shfl_xor(rsL, 32);
        rsH += __shfl_xor(rsH, 16); rsH += __shfl_xor(rsH, 32);
        const float iL = 1.0f / rsL, iH = 1.0f / rsH;
#pragma unroll
        for (int t = 0; t < 4; ++t) {
            *(ushort4*)&ctx[(rowbase + qgL) * 1024 + cbase + t * 16 + quad * 4] =
                pk4(oL[t][0] * iL, oL[t][1] * iL, oL[t][2] * iL, oL[t][3] * iL);
            *(ushort4*)&ctx[(rowbase + qgH) * 1024 + cbase + t * 16 + quad * 4] =
                pk4(oH[t][0] * iH, oH[t][1] * iH, oH[t][2] * iH, oH[t][3] * iH);
        }
    }
}

extern "C" void kernel_launch(void* const* d_in, const int* in_sizes, int n_in,
                              void* d_out, int out_size, void* d_ws, size_t ws_size,
                              hipStream_t stream) {
    const float* x  = (const float*)d_in[0];
    const float* Wq = (const float*)d_in[1];
    const float* bq = (const float*)d_in[2];
    const float* Wk = (const float*)d_in[3];
    const float* bk = (const float*)d_in[4];
    const float* Wv = (const float*)d_in[5];
    const float* bv = (const float*)d_in[6];
    const float* Wo = (const float*)d_in[7];
    const float* bo = (const float*)d_in[8];
    float* out = (float*)d_out;

    const int N = 1024, K = 1024;
    const int M = in_sizes[0] / K;           // 4096
    const size_t MN = (size_t)M * N;
    const size_t WN = (size_t)N * K;

    u16* xb  = (u16*)d_ws;
    u16* wqb = xb  + MN;
    u16* wkb = wqb + WN;
    u16* wvb = wkb + WN;
    u16* wob = wvb + WN;
    u16* q   = wob + WN;
    u16* kb  = q   + MN;
    u16* vt  = kb  + MN;                     // V^T: [b*1024 + h*64 + d][s]
    u16* ctx = q;                            // alias: disjoint per-wave strips

    cast1<<<dim3((int)(MN / 4 / 256)), 256, 0, stream>>>(x, xb, (int)MN);
    cast4<<<dim3((int)(WN / 4 / 256), 4), 256, 0, stream>>>(
        Wq, Wk, Wv, Wo, wqb, wkb, wvb, wob, (int)WN);

    const int gemmBlocks = (M / 128) * (N / 128);     // 256

    gemm128<u16><<<dim3(gemmBlocks, 3), 256, 0, stream>>>(
        xb, wqb, wkb, wvb, bq, bk, bv, q, kb, /*unused*/ q, vt, M, N, K);

    // 1D grid, (h,b) in low 5 bits for XCD L2 locality
    attn5<<<dim3(1024), 256, 0, stream>>>(q, kb, vt, ctx);

    gemm128<float><<<dim3(gemmBlocks, 1), 256, 0, stream>>>(
        ctx, wob, wob, wob, bo, bo, bo, out, out, out, nullptr, M, N, K);
}

// Round 11
// 261.859 us; speedup vs baseline: 1.9344x; 1.0111x over previous
//
#include <hip/hip_runtime.h>
#include <stdint.h>

typedef unsigned short u16;
typedef __bf16 bf16x8 __attribute__((ext_vector_type(8)));
typedef __bf16 bf16x4v __attribute__((ext_vector_type(4)));
typedef float f32x4 __attribute__((ext_vector_type(4)));

typedef __attribute__((address_space(3))) uint32_t lds_u32;
typedef __attribute__((address_space(1))) uint32_t glb_u32;

__device__ __forceinline__ f32x4 mfma16(bf16x8 a, bf16x8 b, f32x4 c) {
    return __builtin_amdgcn_mfma_f32_16x16x32_bf16(a, b, c, 0, 0, 0);
}

__device__ __forceinline__ u16 f2b(float f) {
    union { float f; unsigned u32; } v; v.f = f;
    unsigned b = v.u32;
    unsigned r = b + 0x7FFFu + ((b >> 16) & 1u);   // RNE
    return (u16)(r >> 16);
}

// 4x f32 -> bf16 via native cvt (RNE), reinterpreted as ushort4
__device__ __forceinline__ ushort4 pk4(float a, float b, float c, float d) {
    bf16x4v v;
    v[0] = (__bf16)a; v[1] = (__bf16)b; v[2] = (__bf16)c; v[3] = (__bf16)d;
    union { bf16x4v v; ushort4 u; } cv; cv.v = v; return cv.u;
}

// async global->LDS, 16B per lane (LDS dest = wave base + lane*16)
__device__ __forceinline__ void async16(const u16* g, u16* l) {
    __builtin_amdgcn_global_load_lds((glb_u32*)(uintptr_t)(const void*)g,
                                     (lds_u32*)l, 16, 0, 0);
}

// ---------------------------------------------------------------------------
// fp32 -> bf16 casts
// ---------------------------------------------------------------------------
__global__ __launch_bounds__(256) void cast1(const float* __restrict__ in,
                                             u16* __restrict__ out, int n) {
    const int i = (blockIdx.x * 256 + threadIdx.x) * 4;
    if (i < n) {
        float4 v = *(const float4*)(in + i);
        ushort4 o = { f2b(v.x), f2b(v.y), f2b(v.z), f2b(v.w) };
        *(ushort4*)(out + i) = o;
    }
}

__global__ __launch_bounds__(256) void cast4(
    const float* __restrict__ i0, const float* __restrict__ i1,
    const float* __restrict__ i2, const float* __restrict__ i3,
    u16* __restrict__ o0, u16* __restrict__ o1,
    u16* __restrict__ o2, u16* __restrict__ o3, int n) {
    const int s = blockIdx.y;
    const float* in = s == 0 ? i0 : (s == 1 ? i1 : (s == 2 ? i2 : i3));
    u16* out       = s == 0 ? o0 : (s == 1 ? o1 : (s == 2 ? o2 : o3));
    const int i = (blockIdx.x * 256 + threadIdx.x) * 4;
    if (i < n) {
        float4 v = *(const float4*)(in + i);
        ushort4 o = { f2b(v.x), f2b(v.y), f2b(v.z), f2b(v.w) };
        *(ushort4*)(out + i) = o;
    }
}

// ---------------------------------------------------------------------------
// m97-style QKV GEMM. sel==2 (V) stores TRANSPOSED via an LDS tile transpose:
// round-6..10 wrote ushort4 at 4KB lane stride (16 lines/instr, 8B each);
// now C-subtiles bounce through Tb[32][136] and go out as 128B-contiguous
// runs along the s dimension.
// ---------------------------------------------------------------------------
__global__ __launch_bounds__(256) void gemm_qkv(
    const u16* __restrict__ A,
    const u16* __restrict__ W0, const u16* __restrict__ W1, const u16* __restrict__ W2,
    const float* __restrict__ B0, const float* __restrict__ B1, const float* __restrict__ B2,
    u16* __restrict__ O0, u16* __restrict__ O1,
    u16* __restrict__ VT,
    int M, int N, int K)
{
    const int sel = blockIdx.y;
    const u16* W      = sel == 0 ? W0 : (sel == 1 ? W1 : W2);
    const float* bias = sel == 0 ? B0 : (sel == 1 ? B1 : B2);
    u16* O            = sel == 0 ? O0 : O1;   // sel==2 uses VT path

    __shared__ __attribute__((aligned(16))) u16 As[128 * 32];
    __shared__ __attribute__((aligned(16))) u16 Bs[128 * 32];
    __shared__ __attribute__((aligned(16))) u16 Tb[32][136];   // transpose staging

    const int tid  = threadIdx.x;
    const int lane = tid & 63;
    const int w    = tid >> 6;
    const int l15  = lane & 15;
    const int quad = lane >> 4;

    const int tn = (blockIdx.x & 7) << 7;
    const int tm = (blockIdx.x >> 3) << 7;
    const int wm = (w >> 1) << 6;
    const int wn = (w & 1) << 6;

    f32x4 acc[4][4];
#pragma unroll
    for (int i = 0; i < 4; ++i)
#pragma unroll
        for (int j = 0; j < 4; ++j) acc[i][j] = f32x4{0.f, 0.f, 0.f, 0.f};

    const int lr = lane >> 2;
    const int lc = (lane & 3) << 3;
    const u16* Ag0 = A + (size_t)(tm + 32 * w + lr) * K + lc;
    const u16* Ag1 = Ag0 + (size_t)16 * K;
    const u16* Wg0 = W + (size_t)(tn + 32 * w + lr) * K + lc;
    const u16* Wg1 = Wg0 + (size_t)16 * K;
    u16* Al0 = &As[(32 * w + lr) * 32 + lc];
    u16* Al1 = &As[(32 * w + 16 + lr) * 32 + lc];
    u16* Bl0 = &Bs[(32 * w + lr) * 32 + lc];
    u16* Bl1 = &Bs[(32 * w + 16 + lr) * 32 + lc];

    for (int k0 = 0; k0 < K; k0 += 32) {
        __syncthreads();
        async16(Ag0 + k0, Al0);
        async16(Ag1 + k0, Al1);
        async16(Wg0 + k0, Bl0);
        async16(Wg1 + k0, Bl1);
        asm volatile("s_waitcnt vmcnt(0)" ::: "memory");
        __syncthreads();

        bf16x8 a[4], b[4];
#pragma unroll
        for (int i = 0; i < 4; ++i)
            a[i] = *(const bf16x8*)&As[(wm + 16 * i + l15) * 32 + quad * 8];
#pragma unroll
        for (int j = 0; j < 4; ++j)
            b[j] = *(const bf16x8*)&Bs[(wn + 16 * j + l15) * 32 + quad * 8];
#pragma unroll
        for (int i = 0; i < 4; ++i)
#pragma unroll
            for (int j = 0; j < 4; ++j)
                acc[i][j] = mfma16(a[i], b[j], acc[i][j]);
    }

    if (sel == 2) {
        // coalesced transposed store via LDS: 4 column-chunks of 32
        const int bb = tm >> 11;
        const int s0 = tm & 2047;
        const size_t vtb = ((size_t)bb << 10) + tn;
        for (int c32 = 0; c32 < 128; c32 += 32) {
            __syncthreads();                    // prior chunk's reads done
            if ((c32 >> 6) == (wn >> 6)) {      // this wave's cols intersect chunk
                const int j0 = (c32 >> 4) & 2;
#pragma unroll
                for (int jj = 0; jj < 2; ++jj) {
                    const int j  = j0 + jj;
                    const int cc = jj * 16 + l15;
                    const float bj = bias[tn + wn + 16 * j + l15];
#pragma unroll
                    for (int i = 0; i < 4; ++i) {
                        const int rr = wm + 16 * i + quad * 4;
                        *(ushort4*)&Tb[cc][rr] =
                            pk4(acc[i][j][0] + bj, acc[i][j][1] + bj,
                                acc[i][j][2] + bj, acc[i][j][3] + bj);
                    }
                }
            }
            __syncthreads();                    // Tb chunk visible
            {
                const int c  = tid >> 3;        // col in chunk (0..31)
                const int ss = (tid & 7) * 16;  // s segment (16 u16 = 32B)
                uint4 v0 = *(const uint4*)&Tb[c][ss];
                uint4 v1 = *(const uint4*)&Tb[c][ss + 8];
                u16* dst = &VT[(vtb + c32 + c) * 2048 + s0 + ss];
                *(uint4*)dst       = v0;
                *(uint4*)(dst + 8) = v1;
            }
        }
    } else {
#pragma unroll
        for (int j = 0; j < 4; ++j) {
            const int col = tn + wn + 16 * j + l15;
            const float bj = bias[col];
#pragma unroll
            for (int i = 0; i < 4; ++i) {
                const int row = tm + wm + 16 * i + quad * 4;
#pragma unroll
                for (int r = 0; r < 4; ++r)
                    O[(size_t)(row + r) * N + col] = f2b(acc[i][j][r] + bj);
            }
        }
    }
}

// ---------------------------------------------------------------------------
// Output projection GEMM, 128(M)x64(N) tiles -> 512 blocks = 2 blocks/CU.
// Round-10's 128x128 gave only 256 blocks = 1/CU: every barrier/vmcnt drain
// stalled the CU with nothing co-resident to cover it. 8 MFMA per 3 staging
// loads per wave (vs 16/4) trades density for 2x occupancy.
// ---------------------------------------------------------------------------
__global__ __launch_bounds__(256) void gemm_out64(
    const u16* __restrict__ A, const u16* __restrict__ W,
    const float* __restrict__ bias, float* __restrict__ O,
    int M, int N, int K)
{
    __shared__ __attribute__((aligned(16))) u16 As[128 * 32];
    __shared__ __attribute__((aligned(16))) u16 Bs[64 * 32];

    const int tid  = threadIdx.x;
    const int lane = tid & 63;
    const int w    = tid >> 6;
    const int l15  = lane & 15;
    const int quad = lane >> 4;

    const int tn = (blockIdx.x & 15) << 6;     // N/64 = 16
    const int tm = (blockIdx.x >> 4) << 7;     // M/128 = 32
    const int wm = (w >> 1) << 6;              // {0,64}
    const int wn = (w & 1) << 5;               // {0,32}

    f32x4 acc[4][2];
#pragma unroll
    for (int i = 0; i < 4; ++i)
#pragma unroll
        for (int j = 0; j < 2; ++j) acc[i][j] = f32x4{0.f, 0.f, 0.f, 0.f};

    const int lr = lane >> 2;
    const int lc = (lane & 3) << 3;
    const u16* Ag0 = A + (size_t)(tm + 32 * w + lr) * K + lc;
    const u16* Ag1 = Ag0 + (size_t)16 * K;
    const u16* Wg  = W + (size_t)(tn + 16 * w + lr) * K + lc;
    u16* Al0 = &As[(32 * w + lr) * 32 + lc];
    u16* Al1 = &As[(32 * w + 16 + lr) * 32 + lc];
    u16* Bl  = &Bs[(16 * w + lr) * 32 + lc];

    for (int k0 = 0; k0 < K; k0 += 32) {
        __syncthreads();
        async16(Ag0 + k0, Al0);
        async16(Ag1 + k0, Al1);
        async16(Wg + k0, Bl);
        asm volatile("s_waitcnt vmcnt(0)" ::: "memory");
        __syncthreads();

        bf16x8 a[4], b[2];
#pragma unroll
        for (int i = 0; i < 4; ++i)
            a[i] = *(const bf16x8*)&As[(wm + 16 * i + l15) * 32 + quad * 8];
#pragma unroll
        for (int j = 0; j < 2; ++j)
            b[j] = *(const bf16x8*)&Bs[(wn + 16 * j + l15) * 32 + quad * 8];
#pragma unroll
        for (int i = 0; i < 4; ++i)
#pragma unroll
            for (int j = 0; j < 2; ++j)
                acc[i][j] = mfma16(a[i], b[j], acc[i][j]);
    }

#pragma unroll
    for (int j = 0; j < 2; ++j) {
        const int col = tn + wn + 16 * j + l15;
        const float bj = bias[col];
#pragma unroll
        for (int i = 0; i < 4; ++i) {
            const int row = tm + wm + 16 * i + quad * 4;
#pragma unroll
            for (int r = 0; r < 4; ++r)
                O[(size_t)(row + r) * N + col] = acc[i][j][r] + bj;
        }
    }
}

// ---------------------------------------------------------------------------
// attn5: UNCHANGED from round 10 (fixed-max softmax, 2-way K-split, XCD
// swizzle). Frozen this round for attribution.
// ---------------------------------------------------------------------------
__device__ __forceinline__ void load_ktile(const u16* __restrict__ base, int kt,
                                           int l15, int quad, bf16x8 kf[4][2]) {
#pragma unroll
    for (int t = 0; t < 4; ++t) {
        const u16* kp = base + (size_t)(kt * 64 + t * 16 + l15) * 1024 + quad * 8;
        kf[t][0] = *(const bf16x8*)kp;
        kf[t][1] = *(const bf16x8*)(kp + 32);
    }
}
__device__ __forceinline__ void load_vtile(const u16* __restrict__ base, int kt,
                                           int l15, int quad, bf16x8 vf[4][2]) {
#pragma unroll
    for (int t = 0; t < 4; ++t) {
        const u16* vp = base + (size_t)(t * 16 + l15) * 2048 + kt * 64 + quad * 8;
        vf[t][0] = *(const bf16x8*)vp;
        vf[t][1] = *(const bf16x8*)(vp + 32);
    }
}

__global__ __launch_bounds__(256) void attn5(
    const u16* __restrict__ Q, const u16* __restrict__ Kb,
    const u16* __restrict__ VT, u16* __restrict__ ctx)
{
    __shared__ __attribute__((aligned(16))) u16 Pt[4][32][72];
    __shared__ __attribute__((aligned(16))) float Mg[2][64][34];

    const int lane = threadIdx.x & 63;
    const int wid  = threadIdx.x >> 6;
    const int l15  = lane & 15;
    const int quad = lane >> 4;

    const int hb = blockIdx.x & 31;
    const int h  = hb & 15;
    const int b  = hb >> 4;
    const int pairGroup = blockIdx.x >> 5;

    const int pairIdx = pairGroup * 2 + (wid >> 1);
    const int pib = wid >> 1;
    const int p   = wid & 1;
    const int sL = pairIdx, sH = 127 - pairIdx;
    const int KL = sL >> 2, KH = sH >> 2;

    const size_t rowbase = (size_t)b * 2048;
    const int cbase = h * 64;
    const u16* kbase = Kb + rowbase * 1024 + cbase;
    const u16* vbase = VT + ((size_t)b * 1024 + cbase) * 2048;

    const int qgL = sL * 16 + l15, qgH = sH * 16 + l15;

    const u16* qpL = Q + (rowbase + qgL) * 1024 + cbase + quad * 8;
    const u16* qpH = Q + (rowbase + qgH) * 1024 + cbase + quad * 8;
    const bf16x8 qL0 = *(const bf16x8*)qpL, qL1 = *(const bf16x8*)(qpL + 32);
    const bf16x8 qH0 = *(const bf16x8*)qpH, qH1 = *(const bf16x8*)(qpH + 32);

    f32x4 oL[4], oH[4];
#pragma unroll
    for (int i = 0; i < 4; ++i) { oL[i] = f32x4{0,0,0,0}; oH[i] = f32x4{0,0,0,0}; }
    float rsL = 0.f, rsH = 0.f;
    const float SC = 0.18033688011112042f;

    u16 (*ptw)[72] = Pt[wid];

    bf16x8 kc[4][2], kn[4][2], vf[4][2];
    load_ktile(kbase, p, l15, quad, kc);

    for (int kt = p; kt <= KH; kt += 2) {
        load_vtile(vbase, kt, l15, quad, vf);
        if (kt + 2 <= KH) load_ktile(kbase, kt + 2, l15, quad, kn);
        const bool doL = (kt <= KL);
        const bool mskH = (kt == KH), mskL = (kt == KL);

        float pH[4][4], pL[4][4];
#pragma unroll
        for (int t = 0; t < 4; ++t) {
            f32x4 z = {0,0,0,0};
            z = mfma16(kc[t][0], qH0, z);
            z = mfma16(kc[t][1], qH1, z);
#pragma unroll
            for (int r = 0; r < 4; ++r) {
                float v = fmaf(z[r], SC, -16.0f);
                if (mskH && (kt * 64 + t * 16 + quad * 4 + r) > qgH) v = -1e30f;
                const float e = exp2f(v);
                pH[t][r] = e; rsH += e;
            }
        }
        if (doL) {
#pragma unroll
            for (int t = 0; t < 4; ++t) {
                f32x4 z = {0,0,0,0};
                z = mfma16(kc[t][0], qL0, z);
                z = mfma16(kc[t][1], qL1, z);
#pragma unroll
                for (int r = 0; r < 4; ++r) {
                    float v = fmaf(z[r], SC, -16.0f);
                    if (mskL && (kt * 64 + t * 16 + quad * 4 + r) > qgL) v = -1e30f;
                    const float e = exp2f(v);
                    pL[t][r] = e; rsL += e;
                }
            }
        }

#pragma unroll
        for (int t = 0; t < 4; ++t)
            *(ushort4*)&ptw[16 + l15][t * 16 + quad * 4] =
                pk4(pH[t][0], pH[t][1], pH[t][2], pH[t][3]);
        if (doL) {
#pragma unroll
            for (int t = 0; t < 4; ++t)
                *(ushort4*)&ptw[l15][t * 16 + quad * 4] =
                    pk4(pL[t][0], pL[t][1], pL[t][2], pL[t][3]);
        }

        const bf16x8 bH0 = *(const bf16x8*)&ptw[16 + l15][quad * 8];
        const bf16x8 bH1 = *(const bf16x8*)&ptw[16 + l15][32 + quad * 8];
#pragma unroll
        for (int t = 0; t < 4; ++t) {
            oH[t] = mfma16(vf[t][0], bH0, oH[t]);
            oH[t] = mfma16(vf[t][1], bH1, oH[t]);
        }
        if (doL) {
            const bf16x8 bL0 = *(const bf16x8*)&ptw[l15][quad * 8];
            const bf16x8 bL1 = *(const bf16x8*)&ptw[l15][32 + quad * 8];
#pragma unroll
            for (int t = 0; t < 4; ++t) {
                oL[t] = mfma16(vf[t][0], bL0, oL[t]);
                oL[t] = mfma16(vf[t][1], bL1, oL[t]);
            }
        }

#pragma unroll
        for (int t = 0; t < 4; ++t) { kc[t][0] = kn[t][0]; kc[t][1] = kn[t][1]; }
    }

    if (p == 1) {
        float* my = &Mg[pib][lane][0];
#pragma unroll
        for (int t = 0; t < 4; ++t)
#pragma unroll
            for (int r = 0; r < 4; ++r) {
                my[t * 4 + r]      = oL[t][r];
                my[16 + t * 4 + r] = oH[t][r];
            }
        my[32] = rsL; my[33] = rsH;
    }
    __syncthreads();
    if (p == 0) {
        const float* ot = &Mg[pib][lane][0];
#pragma unroll
        for (int t = 0; t < 4; ++t)
#pragma unroll
            for (int r = 0; r < 4; ++r) {
                oL[t][r] += ot[t * 4 + r];
                oH[t][r] += ot[16 + t * 4 + r];
            }
        rsL += ot[32]; rsH += ot[33];
        rsL += __shfl_xor(rsL, 16); rsL += __shfl_xor(rsL, 32);
        rsH += __shfl_xor(rsH, 16); rsH += __shfl_xor(rsH, 32);
        const float iL = 1.0f / rsL, iH = 1.0f / rsH;
#pragma unroll
        for (int t = 0; t < 4; ++t) {
            *(ushort4*)&ctx[(rowbase + qgL) * 1024 + cbase + t * 16 + quad * 4] =
                pk4(oL[t][0] * iL, oL[t][1] * iL, oL[t][2] * iL, oL[t][3] * iL);
            *(ushort4*)&ctx[(rowbase + qgH) * 1024 + cbase + t * 16 + quad * 4] =
                pk4(oH[t][0] * iH, oH[t][1] * iH, oH[t][2] * iH, oH[t][3] * iH);
        }
    }
}

extern "C" void kernel_launch(void* const* d_in, const int* in_sizes, int n_in,
                              void* d_out, int out_size, void* d_ws, size_t ws_size,
                              hipStream_t stream) {
    const float* x  = (const float*)d_in[0];
    const float* Wq = (const float*)d_in[1];
    const float* bq = (const float*)d_in[2];
    const float* Wk = (const float*)d_in[3];
    const float* bk = (const float*)d_in[4];
    const float* Wv = (const float*)d_in[5];
    const float* bv = (const float*)d_in[6];
    const float* Wo = (const float*)d_in[7];
    const float* bo = (const float*)d_in[8];
    float* out = (float*)d_out;

    const int N = 1024, K = 1024;
    const int M = in_sizes[0] / K;           // 4096
    const size_t MN = (size_t)M * N;
    const size_t WN = (size_t)N * K;

    u16* xb  = (u16*)d_ws;
    u16* wqb = xb  + MN;
    u16* wkb = wqb + WN;
    u16* wvb = wkb + WN;
    u16* wob = wvb + WN;
    u16* q   = wob + WN;
    u16* kb  = q   + MN;
    u16* vt  = kb  + MN;                     // V^T: [b*1024 + h*64 + d][s]
    u16* ctx = q;                            // alias: disjoint per-wave strips

    cast1<<<dim3((int)(MN / 4 / 256)), 256, 0, stream>>>(x, xb, (int)MN);
    cast4<<<dim3((int)(WN / 4 / 256), 4), 256, 0, stream>>>(
        Wq, Wk, Wv, Wo, wqb, wkb, wvb, wob, (int)WN);

    const int gemmBlocks = (M / 128) * (N / 128);     // 256

    gemm_qkv<<<dim3(gemmBlocks, 3), 256, 0, stream>>>(
        xb, wqb, wkb, wvb, bq, bk, bv, q, kb, vt, M, N, K);

    attn5<<<dim3(1024), 256, 0, stream>>>(q, kb, vt, ctx);

    gemm_out64<<<dim3((M / 128) * (N / 64)), 256, 0, stream>>>(
        ctx, wob, bo, out, M, N, K);
}

// Round 12
// 219.614 us; speedup vs baseline: 2.3065x; 1.1924x over previous
//
#include <hip/hip_runtime.h>
#include <stdint.h>

typedef unsigned short u16;
typedef __bf16 bf16x8 __attribute__((ext_vector_type(8)));
typedef __bf16 bf16x4v __attribute__((ext_vector_type(4)));
typedef float f32x4 __attribute__((ext_vector_type(4)));

typedef __attribute__((address_space(3))) uint32_t lds_u32;
typedef __attribute__((address_space(1))) uint32_t glb_u32;

__device__ __forceinline__ f32x4 mfma16(bf16x8 a, bf16x8 b, f32x4 c) {
    return __builtin_amdgcn_mfma_f32_16x16x32_bf16(a, b, c, 0, 0, 0);
}

__device__ __forceinline__ u16 f2b(float f) {
    union { float f; unsigned u32; } v; v.f = f;
    unsigned b = v.u32;
    unsigned r = b + 0x7FFFu + ((b >> 16) & 1u);   // RNE
    return (u16)(r >> 16);
}

// 4x f32 -> bf16 via native cvt (RNE), reinterpreted as ushort4
__device__ __forceinline__ ushort4 pk4(float a, float b, float c, float d) {
    bf16x4v v;
    v[0] = (__bf16)a; v[1] = (__bf16)b; v[2] = (__bf16)c; v[3] = (__bf16)d;
    union { bf16x4v v; ushort4 u; } cv; cv.v = v; return cv.u;
}

// async global->LDS, 16B per lane (LDS dest = wave base + lane*16)
__device__ __forceinline__ void async16(const u16* g, u16* l) {
    __builtin_amdgcn_global_load_lds((glb_u32*)(uintptr_t)(const void*)g,
                                     (lds_u32*)l, 16, 0, 0);
}

// ---------------------------------------------------------------------------
// fp32 -> bf16 casts, one launch: y==0 -> x (4M elems), y=1..4 -> weights (1M)
// ---------------------------------------------------------------------------
__global__ __launch_bounds__(256) void cast_all(
    const float* __restrict__ x,
    const float* __restrict__ w0, const float* __restrict__ w1,
    const float* __restrict__ w2, const float* __restrict__ w3,
    u16* __restrict__ xo, u16* __restrict__ o0, u16* __restrict__ o1,
    u16* __restrict__ o2, u16* __restrict__ o3)
{
    const int s = blockIdx.y;
    const int i = (blockIdx.x * 256 + threadIdx.x) * 4;
    if (s == 0) {
#pragma unroll
        for (int c = 0; c < 4; ++c) {
            const int j = i + c * (1 << 20);
            float4 v = *(const float4*)(x + j);
            *(ushort4*)(xo + j) = pk4(v.x, v.y, v.z, v.w);
        }
    } else {
        const float* in = s == 1 ? w0 : (s == 2 ? w1 : (s == 3 ? w2 : w3));
        u16* out       = s == 1 ? o0 : (s == 2 ? o1 : (s == 3 ? o2 : o3));
        float4 v = *(const float4*)(in + i);
        *(ushort4*)(out + i) = pk4(v.x, v.y, v.z, v.w);
    }
}

// ---------------------------------------------------------------------------
// m97-style QKV GEMM (unchanged from round 11, passing). sel==2 stores V
// transposed via LDS tile transpose.
// ---------------------------------------------------------------------------
__global__ __launch_bounds__(256) void gemm_qkv(
    const u16* __restrict__ A,
    const u16* __restrict__ W0, const u16* __restrict__ W1, const u16* __restrict__ W2,
    const float* __restrict__ B0, const float* __restrict__ B1, const float* __restrict__ B2,
    u16* __restrict__ O0, u16* __restrict__ O1,
    u16* __restrict__ VT,
    int M, int N, int K)
{
    const int sel = blockIdx.y;
    const u16* W      = sel == 0 ? W0 : (sel == 1 ? W1 : W2);
    const float* bias = sel == 0 ? B0 : (sel == 1 ? B1 : B2);
    u16* O            = sel == 0 ? O0 : O1;

    __shared__ __attribute__((aligned(16))) u16 As[128 * 32];
    __shared__ __attribute__((aligned(16))) u16 Bs[128 * 32];
    __shared__ __attribute__((aligned(16))) u16 Tb[32][136];

    const int tid  = threadIdx.x;
    const int lane = tid & 63;
    const int w    = tid >> 6;
    const int l15  = lane & 15;
    const int quad = lane >> 4;

    const int tn = (blockIdx.x & 7) << 7;
    const int tm = (blockIdx.x >> 3) << 7;
    const int wm = (w >> 1) << 6;
    const int wn = (w & 1) << 6;

    f32x4 acc[4][4];
#pragma unroll
    for (int i = 0; i < 4; ++i)
#pragma unroll
        for (int j = 0; j < 4; ++j) acc[i][j] = f32x4{0.f, 0.f, 0.f, 0.f};

    const int lr = lane >> 2;
    const int lc = (lane & 3) << 3;
    const u16* Ag0 = A + (size_t)(tm + 32 * w + lr) * K + lc;
    const u16* Ag1 = Ag0 + (size_t)16 * K;
    const u16* Wg0 = W + (size_t)(tn + 32 * w + lr) * K + lc;
    const u16* Wg1 = Wg0 + (size_t)16 * K;
    u16* Al0 = &As[(32 * w + lr) * 32 + lc];
    u16* Al1 = &As[(32 * w + 16 + lr) * 32 + lc];
    u16* Bl0 = &Bs[(32 * w + lr) * 32 + lc];
    u16* Bl1 = &Bs[(32 * w + 16 + lr) * 32 + lc];

    for (int k0 = 0; k0 < K; k0 += 32) {
        __syncthreads();
        async16(Ag0 + k0, Al0);
        async16(Ag1 + k0, Al1);
        async16(Wg0 + k0, Bl0);
        async16(Wg1 + k0, Bl1);
        asm volatile("s_waitcnt vmcnt(0)" ::: "memory");
        __syncthreads();

        bf16x8 a[4], b[4];
#pragma unroll
        for (int i = 0; i < 4; ++i)
            a[i] = *(const bf16x8*)&As[(wm + 16 * i + l15) * 32 + quad * 8];
#pragma unroll
        for (int j = 0; j < 4; ++j)
            b[j] = *(const bf16x8*)&Bs[(wn + 16 * j + l15) * 32 + quad * 8];
#pragma unroll
        for (int i = 0; i < 4; ++i)
#pragma unroll
            for (int j = 0; j < 4; ++j)
                acc[i][j] = mfma16(a[i], b[j], acc[i][j]);
    }

    if (sel == 2) {
        const int bb = tm >> 11;
        const int s0 = tm & 2047;
        const size_t vtb = ((size_t)bb << 10) + tn;
        for (int c32 = 0; c32 < 128; c32 += 32) {
            __syncthreads();
            if ((c32 >> 6) == (wn >> 6)) {
                const int j0 = (c32 >> 4) & 2;
#pragma unroll
                for (int jj = 0; jj < 2; ++jj) {
                    const int j  = j0 + jj;
                    const int cc = jj * 16 + l15;
                    const float bj = bias[tn + wn + 16 * j + l15];
#pragma unroll
                    for (int i = 0; i < 4; ++i) {
                        const int rr = wm + 16 * i + quad * 4;
                        *(ushort4*)&Tb[cc][rr] =
                            pk4(acc[i][j][0] + bj, acc[i][j][1] + bj,
                                acc[i][j][2] + bj, acc[i][j][3] + bj);
                    }
                }
            }
            __syncthreads();
            {
                const int c  = tid >> 3;
                const int ss = (tid & 7) * 16;
                uint4 v0 = *(const uint4*)&Tb[c][ss];
                uint4 v1 = *(const uint4*)&Tb[c][ss + 8];
                u16* dst = &VT[(vtb + c32 + c) * 2048 + s0 + ss];
                *(uint4*)dst       = v0;
                *(uint4*)(dst + 8) = v1;
            }
        }
    } else {
#pragma unroll
        for (int j = 0; j < 4; ++j) {
            const int col = tn + wn + 16 * j + l15;
            const float bj = bias[col];
#pragma unroll
            for (int i = 0; i < 4; ++i) {
                const int row = tm + wm + 16 * i + quad * 4;
#pragma unroll
                for (int r = 0; r < 4; ++r)
                    O[(size_t)(row + r) * N + col] = f2b(acc[i][j][r] + bj);
            }
        }
    }
}

// ---------------------------------------------------------------------------
// Output projection GEMM (unchanged from round 11).
// ---------------------------------------------------------------------------
__global__ __launch_bounds__(256) void gemm_out64(
    const u16* __restrict__ A, const u16* __restrict__ W,
    const float* __restrict__ bias, float* __restrict__ O,
    int M, int N, int K)
{
    __shared__ __attribute__((aligned(16))) u16 As[128 * 32];
    __shared__ __attribute__((aligned(16))) u16 Bs[64 * 32];

    const int tid  = threadIdx.x;
    const int lane = tid & 63;
    const int w    = tid >> 6;
    const int l15  = lane & 15;
    const int quad = lane >> 4;

    const int tn = (blockIdx.x & 15) << 6;
    const int tm = (blockIdx.x >> 4) << 7;
    const int wm = (w >> 1) << 6;
    const int wn = (w & 1) << 5;

    f32x4 acc[4][2];
#pragma unroll
    for (int i = 0; i < 4; ++i)
#pragma unroll
        for (int j = 0; j < 2; ++j) acc[i][j] = f32x4{0.f, 0.f, 0.f, 0.f};

    const int lr = lane >> 2;
    const int lc = (lane & 3) << 3;
    const u16* Ag0 = A + (size_t)(tm + 32 * w + lr) * K + lc;
    const u16* Ag1 = Ag0 + (size_t)16 * K;
    const u16* Wg  = W + (size_t)(tn + 16 * w + lr) * K + lc;
    u16* Al0 = &As[(32 * w + lr) * 32 + lc];
    u16* Al1 = &As[(32 * w + 16 + lr) * 32 + lc];
    u16* Bl  = &Bs[(16 * w + lr) * 32 + lc];

    for (int k0 = 0; k0 < K; k0 += 32) {
        __syncthreads();
        async16(Ag0 + k0, Al0);
        async16(Ag1 + k0, Al1);
        async16(Wg + k0, Bl);
        asm volatile("s_waitcnt vmcnt(0)" ::: "memory");
        __syncthreads();

        bf16x8 a[4], b[2];
#pragma unroll
        for (int i = 0; i < 4; ++i)
            a[i] = *(const bf16x8*)&As[(wm + 16 * i + l15) * 32 + quad * 8];
#pragma unroll
        for (int j = 0; j < 2; ++j)
            b[j] = *(const bf16x8*)&Bs[(wn + 16 * j + l15) * 32 + quad * 8];
#pragma unroll
        for (int i = 0; i < 4; ++i)
#pragma unroll
            for (int j = 0; j < 2; ++j)
                acc[i][j] = mfma16(a[i], b[j], acc[i][j]);
    }

#pragma unroll
    for (int j = 0; j < 2; ++j) {
        const int col = tn + wn + 16 * j + l15;
        const float bj = bias[col];
#pragma unroll
        for (int i = 0; i < 4; ++i) {
            const int row = tm + wm + 16 * i + quad * 4;
#pragma unroll
            for (int r = 0; r < 4; ++r)
                O[(size_t)(row + r) * N + col] = acc[i][j][r] + bj;
        }
    }
}

// ---------------------------------------------------------------------------
// attn6: block-shared double-buffered K/V LDS staging.
// Block = 4 waves, 4 consecutive strip-pairs (sL=4g+wid, sH=127-sL) of one
// (b,h): KL=g, KH=31-g identical for all waves -> uniform barriers. K/V
// tiles staged ONCE per block per kt via global_load_lds (16KB/iter vs 64KB
// of per-wave register loads), double-buffered, prefetch issued right after
// the single per-iter barrier. XOR column swizzle (chunk ^= row&3) during
// staging breaks the 128B-row same-bank pattern (16-way -> <=4-way).
// Fixed-max softmax (p=exp2(z*SC-16)) retained from rounds 9-11.
// Tile LDS layout: 16B slot (h*256 + tid) holds row r=tid>>2,
// chunk c = ((tid&3) ^ (r&3)) + 4h of the 64x64 tile.
// ---------------------------------------------------------------------------
__device__ __forceinline__ bf16x8 rdt(const u16* base, int t, int l15, int cc) {
    const int r = t * 16 + l15;
    const int c = (cc & 3) ^ (r & 3);
    return *(const bf16x8*)(base + (cc >> 2) * 2048 + r * 32 + c * 8);
}

__global__ __launch_bounds__(256) void attn6(
    const u16* __restrict__ Q, const u16* __restrict__ Kb,
    const u16* __restrict__ VT, u16* __restrict__ ctx)
{
    __shared__ __attribute__((aligned(16))) u16 Kt[2][4096];
    __shared__ __attribute__((aligned(16))) u16 Vt[2][4096];
    __shared__ __attribute__((aligned(16))) u16 Pt[4][32][72];

    const int tid  = threadIdx.x;
    const int lane = tid & 63;
    const int wid  = tid >> 6;
    const int l15  = lane & 15;
    const int quad = lane >> 4;

    // XCD locality: (h,b) in low 5 bits. g-sequence 0,15,1,14,... pairs
    // heavy+light blocks on the same CU (2 blocks/CU).
    const int hb = blockIdx.x & 31;
    const int h  = hb & 15, b = hb >> 4;
    const int ti = blockIdx.x >> 5;                  // 0..15
    const int g  = (ti & 1) ? (15 - (ti >> 1)) : (ti >> 1);

    const int sL = 4 * g + wid, sH = 127 - sL;
    const int KL = g, KH = 31 - g;                   // uniform across waves

    const size_t rowbase = (size_t)b * 2048;
    const int cbase = h * 64;
    const u16* kbase = Kb + rowbase * 1024 + cbase;
    const u16* vbase = VT + ((size_t)b * 1024 + cbase) * 2048;

    const int qgL = sL * 16 + l15, qgH = sH * 16 + l15;
    const u16* qpL = Q + (rowbase + qgL) * 1024 + cbase + quad * 8;
    const u16* qpH = Q + (rowbase + qgH) * 1024 + cbase + quad * 8;
    const bf16x8 qL0 = *(const bf16x8*)qpL, qL1 = *(const bf16x8*)(qpL + 32);
    const bf16x8 qH0 = *(const bf16x8*)qpH, qH1 = *(const bf16x8*)(qpH + 32);

    // staging source for this thread: row sr, chunk c0 (XOR-swizzled)
    const int sr  = tid >> 2;                        // 0..63
    const int sc0 = (((tid & 3) ^ (sr & 3)) << 3);   // u16 offset of chunk
    const u16* kg = kbase + (size_t)sr * 1024 + sc0; // + kt*65536 per tile
    const u16* vg = vbase + (size_t)sr * 2048 + sc0; // + kt*64 per tile

    f32x4 oL[4], oH[4];
#pragma unroll
    for (int i = 0; i < 4; ++i) { oL[i] = f32x4{0,0,0,0}; oH[i] = f32x4{0,0,0,0}; }
    float rsL = 0.f, rsH = 0.f;
    const float SC = 0.18033688011112042f;           // 0.125 * log2(e)

    u16 (*ptw)[72] = Pt[wid];

    // prologue: stage tile kt=0 into buffer 0
    async16(kg,      &Kt[0][tid * 8]);
    async16(kg + 32, &Kt[0][2048 + tid * 8]);
    async16(vg,      &Vt[0][tid * 8]);
    async16(vg + 32, &Vt[0][2048 + tid * 8]);

    for (int kt = 0; kt <= KH; ++kt) {
        const int cur = kt & 1, nxt = cur ^ 1;
        asm volatile("s_waitcnt vmcnt(0)" ::: "memory");
        __syncthreads();                              // buf[cur] ready, all waves past prev compute
        if (kt < KH) {                                // prefetch kt+1 into buf[nxt]
            const u16* kgn = kg + (size_t)(kt + 1) * 65536;
            const u16* vgn = vg + (kt + 1) * 64;
            async16(kgn,      &Kt[nxt][tid * 8]);
            async16(kgn + 32, &Kt[nxt][2048 + tid * 8]);
            async16(vgn,      &Vt[nxt][tid * 8]);
            async16(vgn + 32, &Vt[nxt][2048 + tid * 8]);
        }
        const u16* KT = Kt[cur];
        const u16* VL = Vt[cur];
        const bool doL = (kt <= KL);
        const bool mH = (kt == KH), mL = (kt == KL);

        float pH[4][4], pL[4][4];
#pragma unroll
        for (int t = 0; t < 4; ++t) {
            const bf16x8 kA = rdt(KT, t, l15, quad);
            const bf16x8 kB = rdt(KT, t, l15, quad + 4);
            f32x4 zH = {0,0,0,0};
            zH = mfma16(kA, qH0, zH);
            zH = mfma16(kB, qH1, zH);
            f32x4 zL = {0,0,0,0};
            if (doL) {
                zL = mfma16(kA, qL0, zL);
                zL = mfma16(kB, qL1, zL);
            }
#pragma unroll
            for (int r = 0; r < 4; ++r) {
                float v = fmaf(zH[r], SC, -16.0f);
                if (mH && (kt * 64 + t * 16 + quad * 4 + r) > qgH) v = -1e30f;
                const float e = exp2f(v);
                pH[t][r] = e; rsH += e;
                if (doL) {
                    float vl = fmaf(zL[r], SC, -16.0f);
                    if (mL && (kt * 64 + t * 16 + quad * 4 + r) > qgL) vl = -1e30f;
                    const float el = exp2f(vl);
                    pL[t][r] = el; rsL += el;
                }
            }
        }

        // P (C-layout) -> wave-private LDS rows [q][key]
#pragma unroll
        for (int t = 0; t < 4; ++t)
            *(ushort4*)&ptw[16 + l15][t * 16 + quad * 4] =
                pk4(pH[t][0], pH[t][1], pH[t][2], pH[t][3]);
        if (doL) {
#pragma unroll
            for (int t = 0; t < 4; ++t)
                *(ushort4*)&ptw[l15][t * 16 + quad * 4] =
                    pk4(pL[t][0], pL[t][1], pL[t][2], pL[t][3]);
        }

        const bf16x8 bH0 = *(const bf16x8*)&ptw[16 + l15][quad * 8];
        const bf16x8 bH1 = *(const bf16x8*)&ptw[16 + l15][32 + quad * 8];
#pragma unroll
        for (int t = 0; t < 4; ++t) {
            const bf16x8 vA = rdt(VL, t, l15, quad);
            const bf16x8 vB = rdt(VL, t, l15, quad + 4);
            oH[t] = mfma16(vA, bH0, oH[t]);
            oH[t] = mfma16(vB, bH1, oH[t]);
        }
        if (doL) {
            const bf16x8 bL0 = *(const bf16x8*)&ptw[l15][quad * 8];
            const bf16x8 bL1 = *(const bf16x8*)&ptw[l15][32 + quad * 8];
#pragma unroll
            for (int t = 0; t < 4; ++t) {
                const bf16x8 vA = rdt(VL, t, l15, quad);
                const bf16x8 vB = rdt(VL, t, l15, quad + 4);
                oL[t] = mfma16(vA, bL0, oL[t]);
                oL[t] = mfma16(vB, bL1, oL[t]);
            }
        }
    }

    // epilogue: per-lane l partials -> 2 shfls, normalize, store both strips
    rsH += __shfl_xor(rsH, 16); rsH += __shfl_xor(rsH, 32);
    rsL += __shfl_xor(rsL, 16); rsL += __shfl_xor(rsL, 32);
    const float iH = 1.0f / rsH, iL = 1.0f / rsL;
#pragma unroll
    for (int t = 0; t < 4; ++t) {
        *(ushort4*)&ctx[(rowbase + qgL) * 1024 + cbase + t * 16 + quad * 4] =
            pk4(oL[t][0] * iL, oL[t][1] * iL, oL[t][2] * iL, oL[t][3] * iL);
        *(ushort4*)&ctx[(rowbase + qgH) * 1024 + cbase + t * 16 + quad * 4] =
            pk4(oH[t][0] * iH, oH[t][1] * iH, oH[t][2] * iH, oH[t][3] * iH);
    }
}

extern "C" void kernel_launch(void* const* d_in, const int* in_sizes, int n_in,
                              void* d_out, int out_size, void* d_ws, size_t ws_size,
                              hipStream_t stream) {
    const float* x  = (const float*)d_in[0];
    const float* Wq = (const float*)d_in[1];
    const float* bq = (const float*)d_in[2];
    const float* Wk = (const float*)d_in[3];
    const float* bk = (const float*)d_in[4];
    const float* Wv = (const float*)d_in[5];
    const float* bv = (const float*)d_in[6];
    const float* Wo = (const float*)d_in[7];
    const float* bo = (const float*)d_in[8];
    float* out = (float*)d_out;

    const int N = 1024, K = 1024;
    const int M = in_sizes[0] / K;           // 4096
    const size_t MN = (size_t)M * N;
    const size_t WN = (size_t)N * K;

    u16* xb  = (u16*)d_ws;
    u16* wqb = xb  + MN;
    u16* wkb = wqb + WN;
    u16* wvb = wkb + WN;
    u16* wob = wvb + WN;
    u16* q   = wob + WN;
    u16* kb  = q   + MN;
    u16* vt  = kb  + MN;                     // V^T: [b*1024 + h*64 + d][s]
    u16* ctx = q;                            // alias: disjoint per-wave strips

    cast_all<<<dim3(1024, 5), 256, 0, stream>>>(
        x, Wq, Wk, Wv, Wo, xb, wqb, wkb, wvb, wob);

    const int gemmBlocks = (M / 128) * (N / 128);     // 256

    gemm_qkv<<<dim3(gemmBlocks, 3), 256, 0, stream>>>(
        xb, wqb, wkb, wvb, bq, bk, bv, q, kb, vt, M, N, K);

    // 512 blocks: (h,b) low 5 bits, complementary g pairing in high bits
    attn6<<<dim3(512), 256, 0, stream>>>(q, kb, vt, ctx);

    gemm_out64<<<dim3((M / 128) * (N / 64)), 256, 0, stream>>>(
        ctx, wob, bo, out, M, N, K);
}

// Round 13
// 202.792 us; speedup vs baseline: 2.4978x; 1.0830x over previous
//
#include <hip/hip_runtime.h>
#include <stdint.h>

typedef unsigned short u16;
typedef __bf16 bf16x8 __attribute__((ext_vector_type(8)));
typedef __bf16 bf16x4v __attribute__((ext_vector_type(4)));
typedef float f32x4 __attribute__((ext_vector_type(4)));

typedef __attribute__((address_space(3))) uint32_t lds_u32;
typedef __attribute__((address_space(1))) uint32_t glb_u32;

__device__ __forceinline__ f32x4 mfma16(bf16x8 a, bf16x8 b, f32x4 c) {
    return __builtin_amdgcn_mfma_f32_16x16x32_bf16(a, b, c, 0, 0, 0);
}

// 4x f32 -> bf16 via native cvt (RNE), reinterpreted as ushort4
__device__ __forceinline__ ushort4 pk4(float a, float b, float c, float d) {
    bf16x4v v;
    v[0] = (__bf16)a; v[1] = (__bf16)b; v[2] = (__bf16)c; v[3] = (__bf16)d;
    union { bf16x4v v; ushort4 u; } cv; cv.v = v; return cv.u;
}

// async global->LDS, 16B per lane (LDS dest = wave base + lane*16)
__device__ __forceinline__ void async16(const u16* g, u16* l) {
    __builtin_amdgcn_global_load_lds((glb_u32*)(uintptr_t)(const void*)g,
                                     (lds_u32*)l, 16, 0, 0);
}

// ---------------------------------------------------------------------------
// fp32 -> bf16 casts (unchanged from round 12)
// ---------------------------------------------------------------------------
__global__ __launch_bounds__(256) void cast_all(
    const float* __restrict__ x,
    const float* __restrict__ w0, const float* __restrict__ w1,
    const float* __restrict__ w2, const float* __restrict__ w3,
    u16* __restrict__ xo, u16* __restrict__ o0, u16* __restrict__ o1,
    u16* __restrict__ o2, u16* __restrict__ o3)
{
    const int s = blockIdx.y;
    const int i = (blockIdx.x * 256 + threadIdx.x) * 4;
    if (s == 0) {
#pragma unroll
        for (int c = 0; c < 4; ++c) {
            const int j = i + c * (1 << 20);
            float4 v = *(const float4*)(x + j);
            *(ushort4*)(xo + j) = pk4(v.x, v.y, v.z, v.w);
        }
    } else {
        const float* in = s == 1 ? w0 : (s == 2 ? w1 : (s == 3 ? w2 : w3));
        u16* out       = s == 1 ? o0 : (s == 2 ? o1 : (s == 3 ? o2 : o3));
        float4 v = *(const float4*)(in + i);
        *(ushort4*)(out + i) = pk4(v.x, v.y, v.z, v.w);
    }
}

// ---------------------------------------------------------------------------
// QKV GEMM, round 13: BK=64 (16 barrier-drains instead of 32, 32 MFMA each),
// XOR chunk swizzle in LDS (2-way instead of 8-way read conflicts), XCD
// rectangle swizzle (XCD x = id&7 owns 8 tm x 12 (tn,sel) -> per-XCD L2
// working set ~5MB vs 14MB; round-12 FETCH was 68.7MB = A re-fetched 8x).
// Tb (V-transpose staging) unioned into As (only live after the K-loop).
// LDS layout: row-major 128x64, 16B chunk c of row r stored at slot c^(r&7).
// ---------------------------------------------------------------------------
__global__ __launch_bounds__(256) void gemm_qkv(
    const u16* __restrict__ A,
    const u16* __restrict__ W0, const u16* __restrict__ W1, const u16* __restrict__ W2,
    const float* __restrict__ B0, const float* __restrict__ B1, const float* __restrict__ B2,
    u16* __restrict__ O0, u16* __restrict__ O1,
    u16* __restrict__ VT,
    int M, int N, int K)
{
    const int x = blockIdx.x & 7;
    const int L = blockIdx.x >> 3;                 // 0..95
    const int tm = (8 * (x >> 1) + (L & 7)) << 7;  // 32 tm tiles
    const int tnsel = 12 * (x & 1) + (L >> 3);     // 0..23
    const int sel = tnsel >> 3;
    const int tn  = (tnsel & 7) << 7;

    const u16* W      = sel == 0 ? W0 : (sel == 1 ? W1 : W2);
    const float* bias = sel == 0 ? B0 : (sel == 1 ? B1 : B2);
    u16* O            = sel == 0 ? O0 : O1;        // sel==2 -> VT path

    __shared__ __attribute__((aligned(16))) u16 As[128 * 64];
    __shared__ __attribute__((aligned(16))) u16 Bs[128 * 64];
    u16 (*Tb)[136] = (u16 (*)[136])As;             // union: post-K-loop only

    const int tid  = threadIdx.x;
    const int lane = tid & 63;
    const int w    = tid >> 6;
    const int l15  = lane & 15;
    const int quad = lane >> 4;

    const int wm = (w >> 1) << 6;
    const int wn = (w & 1) << 6;

    f32x4 acc[4][4];
#pragma unroll
    for (int i = 0; i < 4; ++i)
#pragma unroll
        for (int j = 0; j < 4; ++j) acc[i][j] = f32x4{0.f, 0.f, 0.f, 0.f};

    // staging: wave w rows [32w,32w+32), thread does rows lr,+8,+16,+24.
    // source chunk permuted (lcc ^ lr) so dest stays base + lane*16.
    const int lr  = lane >> 3;                     // 0..7
    const int lcc = lane & 7;                      // dest chunk
    const int scc = lcc ^ lr;                      // source chunk (row&7 == lr)
    const u16* Ag = A + (size_t)(tm + 32 * w + lr) * K + scc * 8;
    const u16* Wg = W + (size_t)(tn + 32 * w + lr) * K + scc * 8;
    u16* Al = &As[(32 * w + lr) * 64 + lcc * 8];
    u16* Bl = &Bs[(32 * w + lr) * 64 + lcc * 8];

    for (int k0 = 0; k0 < K; k0 += 64) {
        __syncthreads();
#pragma unroll
        for (int m = 0; m < 4; ++m) {
            async16(Ag + k0 + (size_t)m * 8 * K, Al + m * 512);
            async16(Wg + k0 + (size_t)m * 8 * K, Bl + m * 512);
        }
        asm volatile("s_waitcnt vmcnt(0)" ::: "memory");
        __syncthreads();

#pragma unroll
        for (int kk = 0; kk < 2; ++kk) {
            bf16x8 a[4], b[4];
#pragma unroll
            for (int i = 0; i < 4; ++i) {
                const int r  = wm + 16 * i + l15;
                const int sl = (kk * 4 + quad) ^ (r & 7);
                a[i] = *(const bf16x8*)&As[r * 64 + sl * 8];
            }
#pragma unroll
            for (int j = 0; j < 4; ++j) {
                const int r  = wn + 16 * j + l15;
                const int sl = (kk * 4 + quad) ^ (r & 7);
                b[j] = *(const bf16x8*)&Bs[r * 64 + sl * 8];
            }
#pragma unroll
            for (int i = 0; i < 4; ++i)
#pragma unroll
                for (int j = 0; j < 4; ++j)
                    acc[i][j] = mfma16(a[i], b[j], acc[i][j]);
        }
    }

    if (sel == 2) {
        // coalesced transposed store via LDS (Tb aliases As; K-loop done)
        const int bb = tm >> 11;
        const int s0 = tm & 2047;
        const size_t vtb = ((size_t)bb << 10) + tn;
        for (int c32 = 0; c32 < 128; c32 += 32) {
            __syncthreads();
            if ((c32 >> 6) == (wn >> 6)) {
                const int j0 = (c32 >> 4) & 2;
#pragma unroll
                for (int jj = 0; jj < 2; ++jj) {
                    const int j  = j0 + jj;
                    const int cc = jj * 16 + l15;
                    const float bj = bias[tn + wn + 16 * j + l15];
#pragma unroll
                    for (int i = 0; i < 4; ++i) {
                        const int rr = wm + 16 * i + quad * 4;
                        *(ushort4*)&Tb[cc][rr] =
                            pk4(acc[i][j][0] + bj, acc[i][j][1] + bj,
                                acc[i][j][2] + bj, acc[i][j][3] + bj);
                    }
                }
            }
            __syncthreads();
            {
                const int c  = tid >> 3;
                const int ss = (tid & 7) * 16;
                uint4 v0 = *(const uint4*)&Tb[c][ss];
                uint4 v1 = *(const uint4*)&Tb[c][ss + 8];
                u16* dst = &VT[(vtb + c32 + c) * 2048 + s0 + ss];
                *(uint4*)dst       = v0;
                *(uint4*)(dst + 8) = v1;
            }
        }
    } else {
#pragma unroll
        for (int j = 0; j < 4; ++j) {
            const int col = tn + wn + 16 * j + l15;
            const float bj = bias[col];
#pragma unroll
            for (int i = 0; i < 4; ++i) {
                const int row = tm + wm + 16 * i + quad * 4;
#pragma unroll
                for (int r = 0; r < 4; ++r) {
                    union { float f; unsigned u; } v; v.f = acc[i][j][r] + bj;
                    unsigned rn = v.u + 0x7FFFu + ((v.u >> 16) & 1u);
                    O[(size_t)(row + r) * N + col] = (u16)(rn >> 16);
                }
            }
        }
    }
}

// ---------------------------------------------------------------------------
// Output projection GEMM, round 13: BK=64 + XOR swizzle + XCD rectangle
// swizzle (XCD x owns 8 tm x 8 tn -> ~3MB working set).
// ---------------------------------------------------------------------------
__global__ __launch_bounds__(256) void gemm_out64(
    const u16* __restrict__ A, const u16* __restrict__ W,
    const float* __restrict__ bias, float* __restrict__ O,
    int M, int N, int K)
{
    __shared__ __attribute__((aligned(16))) u16 As[128 * 64];
    __shared__ __attribute__((aligned(16))) u16 Bs[64 * 64];

    const int x = blockIdx.x & 7;
    const int L = blockIdx.x >> 3;                 // 0..63
    const int tm = (8 * (x >> 1) + (L & 7)) << 7;  // 32 tiles
    const int tn = (8 * (x & 1) + (L >> 3)) << 6;  // 16 tiles

    const int tid  = threadIdx.x;
    const int lane = tid & 63;
    const int w    = tid >> 6;
    const int l15  = lane & 15;
    const int quad = lane >> 4;

    const int wm = (w >> 1) << 6;
    const int wn = (w & 1) << 5;

    f32x4 acc[4][2];
#pragma unroll
    for (int i = 0; i < 4; ++i)
#pragma unroll
        for (int j = 0; j < 2; ++j) acc[i][j] = f32x4{0.f, 0.f, 0.f, 0.f};

    const int lr  = lane >> 3;
    const int lcc = lane & 7;
    const int scc = lcc ^ lr;
    const u16* Ag = A + (size_t)(tm + 32 * w + lr) * K + scc * 8;
    const u16* Wg = W + (size_t)(tn + 16 * w + lr) * K + scc * 8;
    u16* Al = &As[(32 * w + lr) * 64 + lcc * 8];
    u16* Bl = &Bs[(16 * w + lr) * 64 + lcc * 8];

    for (int k0 = 0; k0 < K; k0 += 64) {
        __syncthreads();
#pragma unroll
        for (int m = 0; m < 4; ++m)
            async16(Ag + k0 + (size_t)m * 8 * K, Al + m * 512);
#pragma unroll
        for (int m = 0; m < 2; ++m)
            async16(Wg + k0 + (size_t)m * 8 * K, Bl + m * 512);
        asm volatile("s_waitcnt vmcnt(0)" ::: "memory");
        __syncthreads();

#pragma unroll
        for (int kk = 0; kk < 2; ++kk) {
            bf16x8 a[4], b[2];
#pragma unroll
            for (int i = 0; i < 4; ++i) {
                const int r  = wm + 16 * i + l15;
                const int sl = (kk * 4 + quad) ^ (r & 7);
                a[i] = *(const bf16x8*)&As[r * 64 + sl * 8];
            }
#pragma unroll
            for (int j = 0; j < 2; ++j) {
                const int r  = wn + 16 * j + l15;
                const int sl = (kk * 4 + quad) ^ (r & 7);
                b[j] = *(const bf16x8*)&Bs[r * 64 + sl * 8];
            }
#pragma unroll
            for (int i = 0; i < 4; ++i)
#pragma unroll
                for (int j = 0; j < 2; ++j)
                    acc[i][j] = mfma16(a[i], b[j], acc[i][j]);
        }
    }

#pragma unroll
    for (int j = 0; j < 2; ++j) {
        const int col = tn + wn + 16 * j + l15;
        const float bj = bias[col];
#pragma unroll
        for (int i = 0; i < 4; ++i) {
            const int row = tm + wm + 16 * i + quad * 4;
#pragma unroll
            for (int r = 0; r < 4; ++r)
                O[(size_t)(row + r) * N + col] = acc[i][j][r] + bj;
        }
    }
}

// ---------------------------------------------------------------------------
// attn6: UNCHANGED from round 12 (block-shared double-buffered K/V staging,
// fixed-max softmax, XCD swizzle). Frozen.
// ---------------------------------------------------------------------------
__device__ __forceinline__ bf16x8 rdt(const u16* base, int t, int l15, int cc) {
    const int r = t * 16 + l15;
    const int c = (cc & 3) ^ (r & 3);
    return *(const bf16x8*)(base + (cc >> 2) * 2048 + r * 32 + c * 8);
}

__global__ __launch_bounds__(256) void attn6(
    const u16* __restrict__ Q, const u16* __restrict__ Kb,
    const u16* __restrict__ VT, u16* __restrict__ ctx)
{
    __shared__ __attribute__((aligned(16))) u16 Kt[2][4096];
    __shared__ __attribute__((aligned(16))) u16 Vt[2][4096];
    __shared__ __attribute__((aligned(16))) u16 Pt[4][32][72];

    const int tid  = threadIdx.x;
    const int lane = tid & 63;
    const int wid  = tid >> 6;
    const int l15  = lane & 15;
    const int quad = lane >> 4;

    const int hb = blockIdx.x & 31;
    const int h  = hb & 15, b = hb >> 4;
    const int ti = blockIdx.x >> 5;
    const int g  = (ti & 1) ? (15 - (ti >> 1)) : (ti >> 1);

    const int sL = 4 * g + wid, sH = 127 - sL;
    const int KL = g, KH = 31 - g;

    const size_t rowbase = (size_t)b * 2048;
    const int cbase = h * 64;
    const u16* kbase = Kb + rowbase * 1024 + cbase;
    const u16* vbase = VT + ((size_t)b * 1024 + cbase) * 2048;

    const int qgL = sL * 16 + l15, qgH = sH * 16 + l15;
    const u16* qpL = Q + (rowbase + qgL) * 1024 + cbase + quad * 8;
    const u16* qpH = Q + (rowbase + qgH) * 1024 + cbase + quad * 8;
    const bf16x8 qL0 = *(const bf16x8*)qpL, qL1 = *(const bf16x8*)(qpL + 32);
    const bf16x8 qH0 = *(const bf16x8*)qpH, qH1 = *(const bf16x8*)(qpH + 32);

    const int sr  = tid >> 2;
    const int sc0 = (((tid & 3) ^ (sr & 3)) << 3);
    const u16* kg = kbase + (size_t)sr * 1024 + sc0;
    const u16* vg = vbase + (size_t)sr * 2048 + sc0;

    f32x4 oL[4], oH[4];
#pragma unroll
    for (int i = 0; i < 4; ++i) { oL[i] = f32x4{0,0,0,0}; oH[i] = f32x4{0,0,0,0}; }
    float rsL = 0.f, rsH = 0.f;
    const float SC = 0.18033688011112042f;

    u16 (*ptw)[72] = Pt[wid];

    async16(kg,      &Kt[0][tid * 8]);
    async16(kg + 32, &Kt[0][2048 + tid * 8]);
    async16(vg,      &Vt[0][tid * 8]);
    async16(vg + 32, &Vt[0][2048 + tid * 8]);

    for (int kt = 0; kt <= KH; ++kt) {
        const int cur = kt & 1, nxt = cur ^ 1;
        asm volatile("s_waitcnt vmcnt(0)" ::: "memory");
        __syncthreads();
        if (kt < KH) {
            const u16* kgn = kg + (size_t)(kt + 1) * 65536;
            const u16* vgn = vg + (kt + 1) * 64;
            async16(kgn,      &Kt[nxt][tid * 8]);
            async16(kgn + 32, &Kt[nxt][2048 + tid * 8]);
            async16(vgn,      &Vt[nxt][tid * 8]);
            async16(vgn + 32, &Vt[nxt][2048 + tid * 8]);
        }
        const u16* KT = Kt[cur];
        const u16* VL = Vt[cur];
        const bool doL = (kt <= KL);
        const bool mH = (kt == KH), mL = (kt == KL);

        float pH[4][4], pL[4][4];
#pragma unroll
        for (int t = 0; t < 4; ++t) {
            const bf16x8 kA = rdt(KT, t, l15, quad);
            const bf16x8 kB = rdt(KT, t, l15, quad + 4);
            f32x4 zH = {0,0,0,0};
            zH = mfma16(kA, qH0, zH);
            zH = mfma16(kB, qH1, zH);
            f32x4 zL = {0,0,0,0};
            if (doL) {
                zL = mfma16(kA, qL0, zL);
                zL = mfma16(kB, qL1, zL);
            }
#pragma unroll
            for (int r = 0; r < 4; ++r) {
                float v = fmaf(zH[r], SC, -16.0f);
                if (mH && (kt * 64 + t * 16 + quad * 4 + r) > qgH) v = -1e30f;
                const float e = exp2f(v);
                pH[t][r] = e; rsH += e;
                if (doL) {
                    float vl = fmaf(zL[r], SC, -16.0f);
                    if (mL && (kt * 64 + t * 16 + quad * 4 + r) > qgL) vl = -1e30f;
                    const float el = exp2f(vl);
                    pL[t][r] = el; rsL += el;
                }
            }
        }

#pragma unroll
        for (int t = 0; t < 4; ++t)
            *(ushort4*)&ptw[16 + l15][t * 16 + quad * 4] =
                pk4(pH[t][0], pH[t][1], pH[t][2], pH[t][3]);
        if (doL) {
#pragma unroll
            for (int t = 0; t < 4; ++t)
                *(ushort4*)&ptw[l15][t * 16 + quad * 4] =
                    pk4(pL[t][0], pL[t][1], pL[t][2], pL[t][3]);
        }

        const bf16x8 bH0 = *(const bf16x8*)&ptw[16 + l15][quad * 8];
        const bf16x8 bH1 = *(const bf16x8*)&ptw[16 + l15][32 + quad * 8];
#pragma unroll
        for (int t = 0; t < 4; ++t) {
            const bf16x8 vA = rdt(VL, t, l15, quad);
            const bf16x8 vB = rdt(VL, t, l15, quad + 4);
            oH[t] = mfma16(vA, bH0, oH[t]);
            oH[t] = mfma16(vB, bH1, oH[t]);
        }
        if (doL) {
            const bf16x8 bL0 = *(const bf16x8*)&ptw[l15][quad * 8];
            const bf16x8 bL1 = *(const bf16x8*)&ptw[l15][32 + quad * 8];
#pragma unroll
            for (int t = 0; t < 4; ++t) {
                const bf16x8 vA = rdt(VL, t, l15, quad);
                const bf16x8 vB = rdt(VL, t, l15, quad + 4);
                oL[t] = mfma16(vA, bL0, oL[t]);
                oL[t] = mfma16(vB, bL1, oL[t]);
            }
        }
    }

    rsH += __shfl_xor(rsH, 16); rsH += __shfl_xor(rsH, 32);
    rsL += __shfl_xor(rsL, 16); rsL += __shfl_xor(rsL, 32);
    const float iH = 1.0f / rsH, iL = 1.0f / rsL;
#pragma unroll
    for (int t = 0; t < 4; ++t) {
        *(ushort4*)&ctx[(rowbase + qgL) * 1024 + cbase + t * 16 + quad * 4] =
            pk4(oL[t][0] * iL, oL[t][1] * iL, oL[t][2] * iL, oL[t][3] * iL);
        *(ushort4*)&ctx[(rowbase + qgH) * 1024 + cbase + t * 16 + quad * 4] =
            pk4(oH[t][0] * iH, oH[t][1] * iH, oH[t][2] * iH, oH[t][3] * iH);
    }
}

extern "C" void kernel_launch(void* const* d_in, const int* in_sizes, int n_in,
                              void* d_out, int out_size, void* d_ws, size_t ws_size,
                              hipStream_t stream) {
    const float* x  = (const float*)d_in[0];
    const float* Wq = (const float*)d_in[1];
    const float* bq = (const float*)d_in[2];
    const float* Wk = (const float*)d_in[3];
    const float* bk = (const float*)d_in[4];
    const float* Wv = (const float*)d_in[5];
    const float* bv = (const float*)d_in[6];
    const float* Wo = (const float*)d_in[7];
    const float* bo = (const float*)d_in[8];
    float* out = (float*)d_out;

    const int N = 1024, K = 1024;
    const int M = in_sizes[0] / K;           // 4096
    const size_t MN = (size_t)M * N;
    const size_t WN = (size_t)N * K;

    u16* xb  = (u16*)d_ws;
    u16* wqb = xb  + MN;
    u16* wkb = wqb + WN;
    u16* wvb = wkb + WN;
    u16* wob = wvb + WN;
    u16* q   = wob + WN;
    u16* kb  = q   + MN;
    u16* vt  = kb  + MN;                     // V^T: [b*1024 + h*64 + d][s]
    u16* ctx = q;                            // alias: disjoint per-wave strips

    cast_all<<<dim3(1024, 5), 256, 0, stream>>>(
        x, Wq, Wk, Wv, Wo, xb, wqb, wkb, wvb, wob);

    // 768 blocks, XCD rectangle decode inside
    gemm_qkv<<<dim3(768), 256, 0, stream>>>(
        xb, wqb, wkb, wvb, bq, bk, bv, q, kb, vt, M, N, K);

    attn6<<<dim3(512), 256, 0, stream>>>(q, kb, vt, ctx);

    gemm_out64<<<dim3(512), 256, 0, stream>>>(
        ctx, wob, bo, out, M, N, K);
}